// Round 1
// baseline (1856.001 us; speedup 1.0000x reference)
//
#include <hip/hip_runtime.h>
#include <hip/hip_bf16.h>
#include <math.h>

#define NB 4
#define NPTS 4096
#define DIM 256
#define NHEAD 4
#define DHEAD 64
#define KNN 16
#define HIDDEN 64
#define FFDIM 1024
#define LN_EPS 1e-5f

__device__ __forceinline__ float gelu_f(float x) {
    return 0.5f * x * (1.0f + erff(x * 0.7071067811865476f));
}

// ---------------------------------------------------------------------------
// KNN: one block (256 threads) per query point. d2 staged in LDS, 16x argmin.
// d2 computed as sq_n + sq_m - 2*dot to match the reference formula.
// ---------------------------------------------------------------------------
__global__ __launch_bounds__(256) void knn_kernel(const float* __restrict__ xyz,
                                                  int* __restrict__ idx_out) {
    int bn = blockIdx.x;            // 0 .. NB*NPTS-1
    int b = bn / NPTS;
    int n = bn % NPTS;
    const float* base = xyz + (size_t)b * NPTS * 3;

    __shared__ float d2[NPTS];      // 16 KB
    __shared__ float red_v[4];
    __shared__ int   red_i[4];

    float qx = base[n * 3 + 0];
    float qy = base[n * 3 + 1];
    float qz = base[n * 3 + 2];
    float sqn = qx * qx + qy * qy + qz * qz;

    for (int m = threadIdx.x; m < NPTS; m += 256) {
        float x = base[m * 3 + 0];
        float y = base[m * 3 + 1];
        float z = base[m * 3 + 2];
        float sqm = x * x + y * y + z * z;
        float dot = qx * x + qy * y + qz * z;
        float d = sqn + sqm - 2.0f * dot;
        d2[m] = (m == n) ? 1e30f : d;
    }
    __syncthreads();

    for (int it = 0; it < KNN; ++it) {
        float bv = 1e38f;
        int bi = 0x7fffffff;
        for (int m = threadIdx.x; m < NPTS; m += 256) {
            float v = d2[m];
            if (v < bv || (v == bv && m < bi)) { bv = v; bi = m; }
        }
        #pragma unroll
        for (int off = 32; off > 0; off >>= 1) {
            float ov = __shfl_down(bv, off);
            int   oi = __shfl_down(bi, off);
            if (ov < bv || (ov == bv && oi < bi)) { bv = ov; bi = oi; }
        }
        int w = threadIdx.x >> 6;
        if ((threadIdx.x & 63) == 0) { red_v[w] = bv; red_i[w] = bi; }
        __syncthreads();
        if (threadIdx.x == 0) {
            float fv = red_v[0]; int fi = red_i[0];
            #pragma unroll
            for (int j = 1; j < 4; ++j)
                if (red_v[j] < fv || (red_v[j] == fv && red_i[j] < fi)) { fv = red_v[j]; fi = red_i[j]; }
            idx_out[(size_t)bn * KNN + it] = fi;
            d2[fi] = 1e30f;
        }
        __syncthreads();
    }
}

// ---------------------------------------------------------------------------
// LayerNorm: one block (256 threads) per row of 256.
// Two-pass (mean, then var of centered) to match np.var.
// ---------------------------------------------------------------------------
__global__ __launch_bounds__(256) void ln_kernel(const float* __restrict__ in,
                                                 const float* __restrict__ g,
                                                 const float* __restrict__ bb,
                                                 float* __restrict__ out) {
    int r = blockIdx.x;
    int t = threadIdx.x;
    float v = in[(size_t)r * DIM + t];

    __shared__ float sw[4];
    __shared__ float sw2[4];

    float s = v;
    #pragma unroll
    for (int off = 32; off > 0; off >>= 1) s += __shfl_down(s, off);
    if ((t & 63) == 0) sw[t >> 6] = s;
    __syncthreads();
    float mean = (sw[0] + sw[1] + sw[2] + sw[3]) * (1.0f / DIM);

    float dlt = v - mean;
    float s2 = dlt * dlt;
    #pragma unroll
    for (int off = 32; off > 0; off >>= 1) s2 += __shfl_down(s2, off);
    if ((t & 63) == 0) sw2[t >> 6] = s2;
    __syncthreads();
    float var = (sw2[0] + sw2[1] + sw2[2] + sw2[3]) * (1.0f / DIM);

    out[(size_t)r * DIM + t] = dlt * rsqrtf(var + LN_EPS) * g[t] + bb[t];
}

// ---------------------------------------------------------------------------
// Tiled f32 GEMM: C[M,N] = act(A[M,K] @ W[K,N](ldw) + bias) (+res) (+=C)
// 64x64 tile, 256 threads, 4x4 micro-tile, K-step 16.
// ---------------------------------------------------------------------------
template <int ACT, bool ACCUM, bool RES>
__global__ __launch_bounds__(256) void gemm_kernel(const float* __restrict__ A,
                                                   const float* __restrict__ W,
                                                   const float* __restrict__ bias,
                                                   const float* __restrict__ res,
                                                   float* __restrict__ C,
                                                   int M, int Nn, int K, int ldw) {
    __shared__ float As[16][68];   // padded: row start 272B = 17*16 (16B aligned)
    __shared__ float Ws[16][68];

    int t = threadIdx.x;
    int m0 = blockIdx.y * 64;
    int n0 = blockIdx.x * 64;
    int tn = (t & 15) * 4;
    int tm = (t >> 4) * 4;

    float acc[4][4] = {};

    for (int k0 = 0; k0 < K; k0 += 16) {
        {
            int kk = t & 15;
            int mrow = t >> 4;  // 0..15
            #pragma unroll
            for (int i = 0; i < 4; ++i)
                As[kk][mrow + 16 * i] = A[(size_t)(m0 + mrow + 16 * i) * K + k0 + kk];
        }
        {
            int nn = t & 63;
            int kk = t >> 6;    // 0..3
            #pragma unroll
            for (int i = 0; i < 4; ++i)
                Ws[kk + 4 * i][nn] = W[(size_t)(k0 + kk + 4 * i) * ldw + n0 + nn];
        }
        __syncthreads();
        #pragma unroll
        for (int kk = 0; kk < 16; ++kk) {
            float4 av = *reinterpret_cast<const float4*>(&As[kk][tm]);
            float4 bv = *reinterpret_cast<const float4*>(&Ws[kk][tn]);
            float a0 = av.x, a1 = av.y, a2 = av.z, a3 = av.w;
            float b0 = bv.x, b1 = bv.y, b2 = bv.z, b3 = bv.w;
            acc[0][0] += a0 * b0; acc[0][1] += a0 * b1; acc[0][2] += a0 * b2; acc[0][3] += a0 * b3;
            acc[1][0] += a1 * b0; acc[1][1] += a1 * b1; acc[1][2] += a1 * b2; acc[1][3] += a1 * b3;
            acc[2][0] += a2 * b0; acc[2][1] += a2 * b1; acc[2][2] += a2 * b2; acc[2][3] += a2 * b3;
            acc[3][0] += a3 * b0; acc[3][1] += a3 * b1; acc[3][2] += a3 * b2; acc[3][3] += a3 * b3;
        }
        __syncthreads();
    }

    #pragma unroll
    for (int i = 0; i < 4; ++i) {
        int m = m0 + tm + i;
        #pragma unroll
        for (int j = 0; j < 4; ++j) {
            int n = n0 + tn + j;
            float v = acc[i][j];
            if (bias) v += bias[n];
            if (ACT == 1) v = gelu_f(v);
            if (RES) v += res[(size_t)m * Nn + n];
            if (ACCUM) v += C[(size_t)m * Nn + n];
            C[(size_t)m * Nn + n] = v;
        }
    }
}

// ---------------------------------------------------------------------------
// Fused neighbor attention: one block (256 threads) per point.
// W_rel2 (64KB) staged in LDS. Thread d owns output dim d; per-head (=per-wave)
// dot via shuffle; v kept in registers (fully unrolled).
// ---------------------------------------------------------------------------
__global__ __launch_bounds__(256) void attn_kernel(const float* __restrict__ xyz,
                                                   const int* __restrict__ idx,
                                                   const float* __restrict__ q,
                                                   const float* __restrict__ k_lin,
                                                   const float* __restrict__ v_lin,
                                                   const float* __restrict__ W_rel1,
                                                   const float* __restrict__ b_rel1,
                                                   const float* __restrict__ W_rel2,
                                                   const float* __restrict__ b_rel2,
                                                   float* __restrict__ out) {
    int bn = blockIdx.x;
    int b = bn / NPTS;
    int n = bn % NPTS;
    int d = threadIdx.x;

    __shared__ float w2[HIDDEN * DIM];   // 64 KB
    __shared__ float hid[HIDDEN];
    __shared__ float sc[NHEAD][KNN];
    __shared__ int   nb[KNN];
    __shared__ float relv[4];

    for (int i = d; i < HIDDEN * DIM; i += 256) w2[i] = W_rel2[i];
    if (d < KNN) nb[d] = idx[(size_t)bn * KNN + d];

    float qd = q[(size_t)bn * DIM + d];
    float qx = xyz[((size_t)b * NPTS + n) * 3 + 0];
    float qy = xyz[((size_t)b * NPTS + n) * 3 + 1];
    float qz = xyz[((size_t)b * NPTS + n) * 3 + 2];

    float vv[KNN];
    __syncthreads();

    #pragma unroll
    for (int j = 0; j < KNN; ++j) {
        int m = nb[j];
        if (d == 0) {
            float dx = xyz[((size_t)b * NPTS + m) * 3 + 0] - qx;
            float dy = xyz[((size_t)b * NPTS + m) * 3 + 1] - qy;
            float dz = xyz[((size_t)b * NPTS + m) * 3 + 2] - qz;
            relv[0] = dx; relv[1] = dy; relv[2] = dz;
            relv[3] = sqrtf(dx * dx + dy * dy + dz * dz);
        }
        __syncthreads();
        if (d < HIDDEN) {
            float h = b_rel1[d];
            #pragma unroll
            for (int c = 0; c < 4; ++c) h += relv[c] * W_rel1[c * HIDDEN + d];
            hid[d] = gelu_f(h);
        }
        __syncthreads();

        float rd = b_rel2[d];
        #pragma unroll 16
        for (int i = 0; i < HIDDEN; ++i) rd += hid[i] * w2[i * DIM + d];

        size_t nbase = ((size_t)b * NPTS + m) * DIM + d;
        float kd = k_lin[nbase] + rd;
        float vd = v_lin[nbase] + rd;
        vv[j] = vd;

        float p = qd * kd;
        #pragma unroll
        for (int off = 32; off > 0; off >>= 1) p += __shfl_down(p, off);
        if ((d & 63) == 0) sc[d >> 6][j] = p * 0.125f;   // 1/sqrt(64)
        __syncthreads();
    }

    int h = d >> 6;
    float mx = -1e38f;
    #pragma unroll
    for (int j = 0; j < KNN; ++j) mx = fmaxf(mx, sc[h][j]);
    float p[KNN];
    float sum = 0.0f;
    #pragma unroll
    for (int j = 0; j < KNN; ++j) { p[j] = expf(sc[h][j] - mx); sum += p[j]; }
    float inv = 1.0f / sum;
    float acc = 0.0f;
    #pragma unroll
    for (int j = 0; j < KNN; ++j) acc += p[j] * vv[j];
    out[(size_t)bn * DIM + d] = acc * inv;
}

// out[i] = res[i] + bias[i % 256]  (seed d_out with feats1 + b_ff2)
__global__ __launch_bounds__(256) void add_bias_res_kernel(const float* __restrict__ res,
                                                           const float* __restrict__ bias,
                                                           float* __restrict__ out) {
    int i = blockIdx.x * 256 + threadIdx.x;
    out[i] = res[i] + bias[i & (DIM - 1)];
}

extern "C" void kernel_launch(void* const* d_in, const int* in_sizes, int n_in,
                              void* d_out, int out_size, void* d_ws, size_t ws_size,
                              hipStream_t stream) {
    const float* xyz    = (const float*)d_in[0];
    const float* feats  = (const float*)d_in[1];
    const float* ln_q_g = (const float*)d_in[2];
    const float* ln_q_b = (const float*)d_in[3];
    const float* Wq     = (const float*)d_in[4];
    const float* bq     = (const float*)d_in[5];
    const float* Wk     = (const float*)d_in[6];
    const float* bk     = (const float*)d_in[7];
    const float* Wv     = (const float*)d_in[8];
    const float* bv     = (const float*)d_in[9];
    const float* W_rel1 = (const float*)d_in[10];
    const float* b_rel1 = (const float*)d_in[11];
    const float* W_rel2 = (const float*)d_in[12];
    const float* b_rel2 = (const float*)d_in[13];
    const float* Wo     = (const float*)d_in[14];
    const float* bo     = (const float*)d_in[15];
    const float* ln_f_g = (const float*)d_in[16];
    const float* ln_f_b = (const float*)d_in[17];
    const float* W_ff1  = (const float*)d_in[18];
    const float* b_ff1  = (const float*)d_in[19];
    const float* W_ff2  = (const float*)d_in[20];
    const float* b_ff2  = (const float*)d_in[21];
    float* out = (float*)d_out;

    const int M = NB * NPTS;                  // 16384
    char* ws = (char*)d_ws;
    int*   idx  = (int*)ws;                   // 1 MB
    float* bufX = (float*)(ws + (1 << 20));   // 16 MB  x -> attn_out
    float* bufQ = bufX + (size_t)M * DIM;     // 16 MB  q -> feats1
    float* bufK = bufQ + (size_t)M * DIM;     // 16 MB  k_lin -> h
    float* bufV = bufK + (size_t)M * DIM;     // 16 MB  v_lin -> ff1 chunk
    (void)ws_size; (void)in_sizes; (void)n_in; (void)out_size;

    knn_kernel<<<M, 256, 0, stream>>>(xyz, idx);
    ln_kernel<<<M, 256, 0, stream>>>(feats, ln_q_g, ln_q_b, bufX);

    dim3 g44(DIM / 64, M / 64);   // (4, 256)
    gemm_kernel<0, false, false><<<g44, 256, 0, stream>>>(bufX, Wq, bq, nullptr, bufQ, M, DIM, DIM, DIM);
    gemm_kernel<0, false, false><<<g44, 256, 0, stream>>>(bufX, Wk, bk, nullptr, bufK, M, DIM, DIM, DIM);
    gemm_kernel<0, false, false><<<g44, 256, 0, stream>>>(bufX, Wv, bv, nullptr, bufV, M, DIM, DIM, DIM);

    attn_kernel<<<M, 256, 0, stream>>>(xyz, idx, bufQ, bufK, bufV,
                                       W_rel1, b_rel1, W_rel2, b_rel2, bufX);

    // feats1 = attn_out @ Wo + bo + feats   -> bufQ
    gemm_kernel<0, false, true><<<g44, 256, 0, stream>>>(bufX, Wo, bo, feats, bufQ, M, DIM, DIM, DIM);

    // h = LN(feats1) -> bufK
    ln_kernel<<<M, 256, 0, stream>>>(bufQ, ln_f_g, ln_f_b, bufK);

    // out = feats1 + b_ff2 (seed), then accumulate 4 FF chunks
    add_bias_res_kernel<<<M * DIM / 256, 256, 0, stream>>>(bufQ, b_ff2, out);

    for (int c = 0; c < 4; ++c) {
        // ff1 chunk: gelu(h @ W_ff1[:, c*256:(c+1)*256] + b_ff1[chunk]) -> bufV
        gemm_kernel<1, false, false><<<g44, 256, 0, stream>>>(bufK, W_ff1 + c * 256, b_ff1 + c * 256,
                                                              nullptr, bufV, M, DIM, DIM, FFDIM);
        // out += bufV @ W_ff2[c*256:(c+1)*256, :]
        gemm_kernel<0, true, false><<<g44, 256, 0, stream>>>(bufV, W_ff2 + (size_t)c * 256 * DIM, nullptr,
                                                             nullptr, out, M, DIM, DIM, DIM);
    }
}

// Round 3
// 787.320 us; speedup vs baseline: 2.3574x; 2.3574x over previous
//
#include <hip/hip_runtime.h>
#include <hip/hip_bf16.h>
#include <math.h>

#define NB 4
#define NPTS 4096
#define DIM 256
#define KNN 16
#define HID 64
#define FFDIM 1024
#define LN_EPS 1e-5f
#define MTOT (NB * NPTS)

typedef __attribute__((ext_vector_type(8))) short short8;
typedef __attribute__((ext_vector_type(4))) float f32x4;

__device__ __forceinline__ float gelu_f(float x) {
    return 0.5f * x * (1.0f + erff(x * 0.7071067811865476f));
}
__device__ __forceinline__ float b2f(ushort u) {
    return __uint_as_float(((unsigned)u) << 16);
}
__device__ __forceinline__ ushort f2b(float f) {
    unsigned u = __float_as_uint(f);
    return (ushort)((u + 0x7fffu + ((u >> 16) & 1u)) >> 16);
}
__device__ __forceinline__ void gload16(const void* g, void* l) {
    __builtin_amdgcn_global_load_lds((const __attribute__((address_space(1))) void*)g,
                                     (__attribute__((address_space(3))) void*)l, 16, 0, 0);
}
// dot of 8 bf16 (packed in uint4) with 8 consecutive f32
__device__ __forceinline__ float dot8(uint4 w, const float* q) {
    float s = 0.f;
    s += b2f((ushort)(w.x & 0xffff)) * q[0]; s += b2f((ushort)(w.x >> 16)) * q[1];
    s += b2f((ushort)(w.y & 0xffff)) * q[2]; s += b2f((ushort)(w.y >> 16)) * q[3];
    s += b2f((ushort)(w.z & 0xffff)) * q[4]; s += b2f((ushort)(w.z >> 16)) * q[5];
    s += b2f((ushort)(w.w & 0xffff)) * q[6]; s += b2f((ushort)(w.w >> 16)) * q[7];
    return s;
}

// ---------------------------------------------------------------------------
// KNN (unchanged from round 1 — validated)
// ---------------------------------------------------------------------------
__global__ __launch_bounds__(256) void knn_kernel(const float* __restrict__ xyz,
                                                  int* __restrict__ idx_out) {
    int bn = blockIdx.x;
    int b = bn / NPTS;
    int n = bn % NPTS;
    const float* base = xyz + (size_t)b * NPTS * 3;

    __shared__ float d2[NPTS];
    __shared__ float red_v[4];
    __shared__ int   red_i[4];

    float qx = base[n * 3 + 0];
    float qy = base[n * 3 + 1];
    float qz = base[n * 3 + 2];
    float sqn = qx * qx + qy * qy + qz * qz;

    for (int m = threadIdx.x; m < NPTS; m += 256) {
        float x = base[m * 3 + 0];
        float y = base[m * 3 + 1];
        float z = base[m * 3 + 2];
        float sqm = x * x + y * y + z * z;
        float dot = qx * x + qy * y + qz * z;
        float d = sqn + sqm - 2.0f * dot;
        d2[m] = (m == n) ? 1e30f : d;
    }
    __syncthreads();

    for (int it = 0; it < KNN; ++it) {
        float bv = 1e38f;
        int bi = 0x7fffffff;
        for (int m = threadIdx.x; m < NPTS; m += 256) {
            float v = d2[m];
            if (v < bv || (v == bv && m < bi)) { bv = v; bi = m; }
        }
        #pragma unroll
        for (int off = 32; off > 0; off >>= 1) {
            float ov = __shfl_down(bv, off);
            int   oi = __shfl_down(bi, off);
            if (ov < bv || (ov == bv && oi < bi)) { bv = ov; bi = oi; }
        }
        int w = threadIdx.x >> 6;
        if ((threadIdx.x & 63) == 0) { red_v[w] = bv; red_i[w] = bi; }
        __syncthreads();
        if (threadIdx.x == 0) {
            float fv = red_v[0]; int fi = red_i[0];
            #pragma unroll
            for (int j = 1; j < 4; ++j)
                if (red_v[j] < fv || (red_v[j] == fv && red_i[j] < fi)) { fv = red_v[j]; fi = red_i[j]; }
            idx_out[(size_t)bn * KNN + it] = fi;
            d2[fi] = 1e30f;
        }
        __syncthreads();
    }
}

// ---------------------------------------------------------------------------
// LayerNorm f32 in -> bf16 out
// ---------------------------------------------------------------------------
__global__ __launch_bounds__(256) void ln_kernel(const float* __restrict__ in,
                                                 const float* __restrict__ g,
                                                 const float* __restrict__ bb,
                                                 ushort* __restrict__ out) {
    int r = blockIdx.x;
    int t = threadIdx.x;
    float v = in[(size_t)r * DIM + t];

    __shared__ float sw[4];
    __shared__ float sw2[4];

    float s = v;
    #pragma unroll
    for (int off = 32; off > 0; off >>= 1) s += __shfl_down(s, off);
    if ((t & 63) == 0) sw[t >> 6] = s;
    __syncthreads();
    float mean = (sw[0] + sw[1] + sw[2] + sw[3]) * (1.0f / DIM);

    float dlt = v - mean;
    float s2 = dlt * dlt;
    #pragma unroll
    for (int off = 32; off > 0; off >>= 1) s2 += __shfl_down(s2, off);
    if ((t & 63) == 0) sw2[t >> 6] = s2;
    __syncthreads();
    float var = (sw2[0] + sw2[1] + sw2[2] + sw2[3]) * (1.0f / DIM);

    out[(size_t)r * DIM + t] = f2b(dlt * rsqrtf(var + LN_EPS) * g[t] + bb[t]);
}

// ---------------------------------------------------------------------------
// Transpose-convert: f32 in[R][C] -> bf16 out[C][R]
// ---------------------------------------------------------------------------
__global__ __launch_bounds__(256) void tconv(const float* __restrict__ in,
                                             ushort* __restrict__ out, int R, int C) {
    __shared__ float tile[32][33];
    int tx = threadIdx.x & 31, ty = threadIdx.x >> 5;   // ty 0..7
    int r0 = blockIdx.y * 32, c0 = blockIdx.x * 32;
    #pragma unroll
    for (int k = 0; k < 4; ++k)
        tile[ty + 8 * k][tx] = in[(size_t)(r0 + ty + 8 * k) * C + c0 + tx];
    __syncthreads();
    #pragma unroll
    for (int k = 0; k < 4; ++k)
        out[(size_t)(c0 + ty + 8 * k) * R + r0 + tx] = f2b(tile[tx][ty + 8 * k]);
}

// straight f32 -> bf16 (exactly n = grid*256 elements)
__global__ __launch_bounds__(256) void conv_k(const float* __restrict__ in,
                                              ushort* __restrict__ out) {
    int i = blockIdx.x * 256 + threadIdx.x;
    out[i] = f2b(in[i]);
}

// ---------------------------------------------------------------------------
// MFMA bf16 GEMM: C[M][N] = act(A[M][K] @ Bt[N][K]^T + bias) (+res)
// 128x128 tile, BK=32, 4 waves (2x2), 16x16x32 MFMA, global_load_lds staging,
// XOR-swizzled LDS (involution applied to global src so it cancels on read).
// ---------------------------------------------------------------------------
template <int ACT, int OUTBF, int RES>
__global__ __launch_bounds__(256) void gemm_bt(
    const ushort* __restrict__ A, const ushort* __restrict__ Bt,
    const float* __restrict__ bias, const float* __restrict__ res,
    void* __restrict__ Cv, int M, int N, int K)
{
    __shared__ ushort As[4096];   // [128][32] bf16, swizzled
    __shared__ ushort Bs[4096];
    const int t = threadIdx.x;
    const int wave = t >> 6, lane = t & 63;
    const int m0 = blockIdx.y * 128, n0 = blockIdx.x * 128;
    const int wr = (wave >> 1) * 64, wc = (wave & 1) * 64;

    f32x4 acc[4][4];
    #pragma unroll
    for (int i = 0; i < 4; ++i)
        #pragma unroll
        for (int j = 0; j < 4; ++j) acc[i][j] = {0.f, 0.f, 0.f, 0.f};

    // staging geometry
    const int rA0 = (wave * 2 + 0) * 16 + (lane >> 2);
    const int rA1 = (wave * 2 + 1) * 16 + (lane >> 2);
    const int u4 = lane & 3;
    const int sw0 = (rA0 + (rA0 >> 2)) & 3;
    const int sw1 = (rA1 + (rA1 >> 2)) & 3;
    char* ldsA0 = (char*)As + (wave * 2 + 0) * 1024 + lane * 16;
    char* ldsA1 = (char*)As + (wave * 2 + 1) * 1024 + lane * 16;
    char* ldsB0 = (char*)Bs + (wave * 2 + 0) * 1024 + lane * 16;
    char* ldsB1 = (char*)Bs + (wave * 2 + 1) * 1024 + lane * 16;
    const size_t aOff0 = (size_t)(m0 + rA0) * K + (size_t)((u4 ^ sw0) * 8);
    const size_t aOff1 = (size_t)(m0 + rA1) * K + (size_t)((u4 ^ sw1) * 8);
    const size_t bOff0 = (size_t)(n0 + rA0) * K + (size_t)((u4 ^ sw0) * 8);
    const size_t bOff1 = (size_t)(n0 + rA1) * K + (size_t)((u4 ^ sw1) * 8);

    const int cl = lane & 15, gq = lane >> 4;

    for (int k0 = 0; k0 < K; k0 += 32) {
        gload16(A + aOff0 + k0, ldsA0);
        gload16(A + aOff1 + k0, ldsA1);
        gload16(Bt + bOff0 + k0, ldsB0);
        gload16(Bt + bOff1 + k0, ldsB1);
        __syncthreads();

        short8 av[4], bv[4];
        #pragma unroll
        for (int mi = 0; mi < 4; ++mi) {
            int row = wr + mi * 16 + cl;
            int s = (row + (row >> 2)) & 3;
            av[mi] = *(const short8*)((const char*)As + row * 64 + ((gq ^ s) << 4));
            int rowb = wc + mi * 16 + cl;
            int sb = (rowb + (rowb >> 2)) & 3;
            bv[mi] = *(const short8*)((const char*)Bs + rowb * 64 + ((gq ^ sb) << 4));
        }
        #pragma unroll
        for (int mi = 0; mi < 4; ++mi)
            #pragma unroll
            for (int ni = 0; ni < 4; ++ni)
                acc[mi][ni] = __builtin_amdgcn_mfma_f32_16x16x32_bf16(av[mi], bv[ni], acc[mi][ni], 0, 0, 0);
        __syncthreads();
    }

    float* Cf = (float*)Cv;
    ushort* Cb = (ushort*)Cv;
    #pragma unroll
    for (int ni = 0; ni < 4; ++ni) {
        int col = n0 + wc + ni * 16 + cl;
        float bvv = bias[col];
        #pragma unroll
        for (int mi = 0; mi < 4; ++mi) {
            #pragma unroll
            for (int r = 0; r < 4; ++r) {
                int row = m0 + wr + mi * 16 + gq * 4 + r;
                float v = acc[mi][ni][r] + bvv;
                if (ACT == 1) v = gelu_f(v);
                if (RES) v += res[(size_t)row * N + col];
                if (OUTBF) Cb[(size_t)row * N + col] = f2b(v);
                else       Cf[(size_t)row * N + col] = v;
            }
        }
    }
}

// ---------------------------------------------------------------------------
// hid = gelu(rel @ W_rel1 + b_rel1) for all (point, neighbor) rows -> bf16
// ---------------------------------------------------------------------------
__global__ __launch_bounds__(256) void hid_kernel(const float* __restrict__ xyz,
                                                  const int* __restrict__ idx,
                                                  const float* __restrict__ W1,
                                                  const float* __restrict__ b1,
                                                  ushort* __restrict__ hid) {
    int t = threadIdx.x;
    int rl = t >> 6, i = t & 63;
    int row = blockIdx.x * 4 + rl;
    int bn = row >> 4;
    int b = bn >> 12;
    int n = bn & (NPTS - 1);
    int m = idx[row];
    const float* xb = xyz + (size_t)b * NPTS * 3;
    float dx = xb[m * 3 + 0] - xb[n * 3 + 0];
    float dy = xb[m * 3 + 1] - xb[n * 3 + 1];
    float dz = xb[m * 3 + 2] - xb[n * 3 + 2];
    float nr = sqrtf(dx * dx + dy * dy + dz * dz);
    float a = b1[i] + dx * W1[i] + dy * W1[64 + i] + dz * W1[128 + i] + nr * W1[192 + i];
    hid[(size_t)row * 64 + i] = f2b(gelu_f(a));
}

// ---------------------------------------------------------------------------
// Attention with factored rel_e:
//   logit_hj = ( q_h . k_j|h  +  qw_h . hid_j ) / 8       (b_rel2 cancels)
//   out_d    = sum_j p_j v_j[d] + sum_i hp_h[i] w2[i][d] + b_rel2[d]
//   qw_h[i] = sum_{d in head h} q_d w2[i][d];  hp_h[i] = sum_j p_hj hid_j[i]
// 8 points per block; wave == head; W_rel2 staged once (bf16, swizzled).
// ---------------------------------------------------------------------------
#define PTS 8
__global__ __launch_bounds__(256) void attn_kernel(
    const int* __restrict__ idx,
    const ushort* __restrict__ qb, const ushort* __restrict__ kb,
    const ushort* __restrict__ vb, const ushort* __restrict__ hidg,
    const ushort* __restrict__ w2b, const float* __restrict__ b_rel2,
    ushort* __restrict__ aob)
{
    __shared__ uint4 w2S4[2048];      // 32KB: [64 rows][32 chunks], chunk u holds global chunk u^(i&7)
    __shared__ uint4 hidS4[16 * 9];   // [16 rows][stride 144B], 8 valid chunks/row
    __shared__ float qS[256];
    __shared__ float qwS[256];
    __shared__ float psS[64];
    __shared__ float hpS[256];
    __shared__ int   nbAll[128];
    ushort* w2S = (ushort*)w2S4;
    ushort* hidS = (ushort*)hidS4;

    const int t = threadIdx.x;
    const int h = t >> 6, lane = t & 63;
    const int blk = blockIdx.x;
    const int bn0 = blk * PTS;
    const int R0 = blk * (PTS * 16);

    #pragma unroll
    for (int s = 0; s < 8; ++s) {
        int ci = t + 256 * s;            // 0..2047
        int i = ci >> 5, u = ci & 31;
        int su = u ^ (i & 7);
        w2S4[ci] = *(const uint4*)(w2b + i * 256 + su * 8);
    }
    if (t < 128) nbAll[t] = idx[R0 + t];
    __syncthreads();

    const float b2d = b_rel2[t];
    const int cd = t >> 3;               // chunk of dim d = t
    const int dlo = t & 7;

    for (int pt = 0; pt < PTS; ++pt) {
        const int bn = bn0 + pt;
        const size_t base = (size_t)(bn >> 12) * NPTS;

        qS[t] = b2f(qb[(size_t)bn * 256 + t]);
        if (t < 128) {
            int j = t >> 3, c = t & 7;
            hidS4[j * 9 + c] = *(const uint4*)(hidg + (size_t)(R0 + pt * 16 + j) * 64 + c * 8);
        }
        __syncthreads();

        // phase 1: qw[h][i]
        {
            int i = lane, si = i & 7;
            float acc = 0.f;
            #pragma unroll
            for (int cc = 0; cc < 8; ++cc) {
                int gc = cc ^ si;                        // global chunk within head
                uint4 w = w2S4[i * 32 + h * 8 + cc];     // holds global chunk h*8+gc
                acc += dot8(w, &qS[h * 64 + gc * 8]);
            }
            qwS[t] = acc;
        }
        __syncthreads();

        // phase 2: logits + softmax (wave h = head h; lane = j*4+sub)
        {
            int j = lane >> 2, sub = lane & 3;
            int m = nbAll[pt * 16 + j];
            const ushort* krow = kb + (base + m) * 256 + h * 64 + sub * 16;
            uint4 ka = *(const uint4*)krow;
            uint4 kc = *(const uint4*)(krow + 8);
            const float* qp = &qS[h * 64 + sub * 16];
            float d1 = dot8(ka, qp) + dot8(kc, qp + 8);
            const ushort* hrow = hidS + j * 72 + sub * 16;
            uint4 ha = *(const uint4*)hrow;
            uint4 hc = *(const uint4*)(hrow + 8);
            const float* qwp = &qwS[h * 64 + sub * 16];
            float d2 = dot8(ha, qwp) + dot8(hc, qwp + 8);
            float pp = d1 + d2;
            pp += __shfl_xor(pp, 1, 64);
            pp += __shfl_xor(pp, 2, 64);
            pp *= 0.125f;
            float mx = pp;
            mx = fmaxf(mx, __shfl_xor(mx, 4, 64));
            mx = fmaxf(mx, __shfl_xor(mx, 8, 64));
            mx = fmaxf(mx, __shfl_xor(mx, 16, 64));
            mx = fmaxf(mx, __shfl_xor(mx, 32, 64));
            float e = expf(pp - mx);
            float ss = e;
            ss += __shfl_xor(ss, 4, 64);
            ss += __shfl_xor(ss, 8, 64);
            ss += __shfl_xor(ss, 16, 64);
            ss += __shfl_xor(ss, 32, 64);       // = sum_j e_j (bits 2..5 = full j range)
            float pj = e / ss;                  // FIX: was e*4/ss (double-counted sub lanes)
            if (sub == 0) psS[h * 16 + j] = pj;
        }
        __syncthreads();

        // phase 3a: hp[h][i]
        {
            int i = lane;
            float acc = 0.f;
            #pragma unroll
            for (int j = 0; j < 16; ++j)
                acc += psS[h * 16 + j] * b2f(hidS[j * 72 + i]);
            hpS[t] = acc;
        }
        __syncthreads();

        // phase 3b: output dim d = t
        {
            float o = b2d;
            #pragma unroll
            for (int j = 0; j < 16; ++j) {
                int m = nbAll[pt * 16 + j];
                o += psS[h * 16 + j] * b2f(vb[(base + m) * 256 + t]);
            }
            #pragma unroll
            for (int i = 0; i < 64; ++i) {
                int u = cd ^ (i & 7);
                float wv = b2f(w2S[i * 256 + u * 8 + dlo]);
                o += hpS[h * 64 + i] * wv;
            }
            aob[(size_t)bn * 256 + t] = f2b(o);
        }
        __syncthreads();
    }
}

// ---------------------------------------------------------------------------
extern "C" void kernel_launch(void* const* d_in, const int* in_sizes, int n_in,
                              void* d_out, int out_size, void* d_ws, size_t ws_size,
                              hipStream_t stream) {
    const float* xyz    = (const float*)d_in[0];
    const float* feats  = (const float*)d_in[1];
    const float* ln_q_g = (const float*)d_in[2];
    const float* ln_q_b = (const float*)d_in[3];
    const float* Wq     = (const float*)d_in[4];
    const float* bq     = (const float*)d_in[5];
    const float* Wk     = (const float*)d_in[6];
    const float* bk     = (const float*)d_in[7];
    const float* Wv     = (const float*)d_in[8];
    const float* bv     = (const float*)d_in[9];
    const float* W_rel1 = (const float*)d_in[10];
    const float* b_rel1 = (const float*)d_in[11];
    const float* W_rel2 = (const float*)d_in[12];
    const float* b_rel2 = (const float*)d_in[13];
    const float* Wo     = (const float*)d_in[14];
    const float* bo     = (const float*)d_in[15];
    const float* ln_f_g = (const float*)d_in[16];
    const float* ln_f_b = (const float*)d_in[17];
    const float* W_ff1  = (const float*)d_in[18];
    const float* b_ff1  = (const float*)d_in[19];
    const float* W_ff2  = (const float*)d_in[20];
    const float* b_ff2  = (const float*)d_in[21];
    (void)in_sizes; (void)n_in; (void)out_size; (void)ws_size;

    char* ws = (char*)d_ws;
    const size_t MB = 1u << 20;
    int*    idx    = (int*)ws;                       // 1 MB
    ushort* xb     = (ushort*)(ws + 1 * MB);         // 8 MB  (LN out; reused as attn out)
    ushort* qb     = (ushort*)(ws + 9 * MB);         // 8 MB  (q; reused as h)
    ushort* kb     = (ushort*)(ws + 17 * MB);        // 8 MB
    ushort* vb     = (ushort*)(ws + 25 * MB);        // 8 MB
    ushort* hidg   = (ushort*)(ws + 33 * MB);        // 32 MB (hid; reused as ff1 out)
    float*  feats1 = (float*)(ws + 65 * MB);         // 16 MB
    ushort* WqT    = (ushort*)(ws + 81 * MB);
    ushort* WkT    = WqT + 65536;
    ushort* WvT    = WkT + 65536;
    ushort* WoT    = WvT + 65536;
    ushort* Wf1T   = WoT + 65536;                    // [1024][256]
    ushort* Wf2T   = Wf1T + 262144;                  // [256][1024]
    ushort* w2b    = Wf2T + 262144;                  // [64][256]
    ushort* aob  = xb;
    ushort* hb   = qb;
    ushort* ff1b = hidg;

    tconv<<<dim3(8, 8),  256, 0, stream>>>(Wq, WqT, 256, 256);
    tconv<<<dim3(8, 8),  256, 0, stream>>>(Wk, WkT, 256, 256);
    tconv<<<dim3(8, 8),  256, 0, stream>>>(Wv, WvT, 256, 256);
    tconv<<<dim3(8, 8),  256, 0, stream>>>(Wo, WoT, 256, 256);
    tconv<<<dim3(32, 8), 256, 0, stream>>>(W_ff1, Wf1T, 256, 1024);
    tconv<<<dim3(8, 32), 256, 0, stream>>>(W_ff2, Wf2T, 1024, 256);
    conv_k<<<64, 256, 0, stream>>>(W_rel2, w2b);

    knn_kernel<<<MTOT, 256, 0, stream>>>(xyz, idx);
    ln_kernel<<<MTOT, 256, 0, stream>>>(feats, ln_q_g, ln_q_b, xb);

    gemm_bt<0, 1, 0><<<dim3(2, 128), 256, 0, stream>>>(xb, WqT, bq, nullptr, qb, MTOT, 256, 256);
    gemm_bt<0, 1, 0><<<dim3(2, 128), 256, 0, stream>>>(xb, WkT, bk, nullptr, kb, MTOT, 256, 256);
    gemm_bt<0, 1, 0><<<dim3(2, 128), 256, 0, stream>>>(xb, WvT, bv, nullptr, vb, MTOT, 256, 256);

    hid_kernel<<<MTOT * 16 / 4, 256, 0, stream>>>(xyz, idx, W_rel1, b_rel1, hidg);
    attn_kernel<<<MTOT / PTS, 256, 0, stream>>>(idx, qb, kb, vb, hidg, w2b, b_rel2, aob);

    // feats1 = attn_out @ Wo + bo + feats
    gemm_bt<0, 0, 1><<<dim3(2, 128), 256, 0, stream>>>(aob, WoT, bo, feats, feats1, MTOT, 256, 256);
    ln_kernel<<<MTOT, 256, 0, stream>>>(feats1, ln_f_g, ln_f_b, hb);
    // ff1 = gelu(h @ W_ff1 + b_ff1)  (bf16)
    gemm_bt<1, 1, 0><<<dim3(8, 128), 256, 0, stream>>>(hb, Wf1T, b_ff1, nullptr, ff1b, MTOT, 1024, 256);
    // out = ff1 @ W_ff2 + b_ff2 + feats1
    gemm_bt<0, 0, 1><<<dim3(2, 128), 256, 0, stream>>>(ff1b, Wf2T, b_ff2, feats1, (float*)d_out, MTOT, 256, 1024);
}

// Round 4
// 566.879 us; speedup vs baseline: 3.2741x; 1.3889x over previous
//
#include <hip/hip_runtime.h>
#include <hip/hip_bf16.h>
#include <math.h>

#define NB 4
#define NPTS 4096
#define DIM 256
#define KNN 16
#define HID 64
#define FFDIM 1024
#define LN_EPS 1e-5f
#define MTOT (NB * NPTS)
#define KINF 3e38f

typedef __attribute__((ext_vector_type(8))) short short8;
typedef __attribute__((ext_vector_type(4))) float f32x4;

__device__ __forceinline__ float gelu_f(float x) {
    return 0.5f * x * (1.0f + erff(x * 0.7071067811865476f));
}
__device__ __forceinline__ float b2f(ushort u) {
    return __uint_as_float(((unsigned)u) << 16);
}
__device__ __forceinline__ ushort f2b(float f) {
    unsigned u = __float_as_uint(f);
    return (ushort)((u + 0x7fffu + ((u >> 16) & 1u)) >> 16);
}
__device__ __forceinline__ void gload16(const void* g, void* l) {
    __builtin_amdgcn_global_load_lds((const __attribute__((address_space(1))) void*)g,
                                     (__attribute__((address_space(3))) void*)l, 16, 0, 0);
}
// dot of 8 bf16 (packed in uint4) with 8 consecutive f32
__device__ __forceinline__ float dot8(uint4 w, const float* q) {
    float s = 0.f;
    s += b2f((ushort)(w.x & 0xffff)) * q[0]; s += b2f((ushort)(w.x >> 16)) * q[1];
    s += b2f((ushort)(w.y & 0xffff)) * q[2]; s += b2f((ushort)(w.y >> 16)) * q[3];
    s += b2f((ushort)(w.z & 0xffff)) * q[4]; s += b2f((ushort)(w.z >> 16)) * q[5];
    s += b2f((ushort)(w.w & 0xffff)) * q[6]; s += b2f((ushort)(w.w >> 16)) * q[7];
    return s;
}

// ---------------------------------------------------------------------------
// KNN v2: one block per query. Each lane holds 16 candidate distances in
// registers (m = t + 256*i). Per wave: 16 extraction rounds of butterfly
// lexicographic argmin on (dist, idx); owning lane masks and recomputes its
// lane-min. One barrier; wave 0 merges 4x16 sorted lists. No LDS scans.
// ---------------------------------------------------------------------------
__global__ __launch_bounds__(256) void knn_kernel(const float* __restrict__ xyz,
                                                  int* __restrict__ idx_out) {
    int bn = blockIdx.x;
    int b = bn >> 12;
    int n = bn & (NPTS - 1);
    const float* base = xyz + (size_t)b * NPTS * 3;
    int t = threadIdx.x;
    int wv = t >> 6, lane = t & 63;

    __shared__ float wval[64];
    __shared__ int   wmS[64];

    float qx = base[n * 3 + 0], qy = base[n * 3 + 1], qz = base[n * 3 + 2];
    float sqn = qx * qx + qy * qy + qz * qz;

    float d[16];
    #pragma unroll
    for (int i = 0; i < 16; ++i) {
        int m = t + 256 * i;
        float x = base[m * 3 + 0], y = base[m * 3 + 1], z = base[m * 3 + 2];
        float sqm = x * x + y * y + z * z;
        float dot = qx * x + qy * y + qz * z;
        float dd = sqn + sqm - 2.0f * dot;
        d[i] = (m == n) ? KINF : dd;
    }
    // maintained lane-min (val, m); strict < keeps smallest m on ties
    float lv = d[0]; int lm = t;
    #pragma unroll
    for (int i = 1; i < 16; ++i) {
        int m = t + 256 * i;
        if (d[i] < lv) { lv = d[i]; lm = m; }
    }

    #pragma unroll 1
    for (int r = 0; r < 16; ++r) {
        float v = lv; int m = lm;
        #pragma unroll
        for (int off = 1; off < 64; off <<= 1) {
            float ov = __shfl_xor(v, off, 64);
            int   om = __shfl_xor(m, off, 64);
            if (ov < v || (ov == v && om < m)) { v = ov; m = om; }
        }
        if (lane == 0) { wval[wv * 16 + r] = v; wmS[wv * 16 + r] = m; }
        if (lm == m) {                       // unique owner (m = t mod 256)
            int pos = lm >> 8;
            #pragma unroll
            for (int i = 0; i < 16; ++i) if (i == pos) d[i] = KINF;
            lv = KINF; lm = 0x7fffffff;
            #pragma unroll
            for (int i = 0; i < 16; ++i) {
                int mi = t + 256 * i;
                if (d[i] < lv) { lv = d[i]; lm = mi; }
            }
        }
    }
    __syncthreads();

    if (wv == 0) {
        float v0 = wval[lane];
        int   m0 = wmS[lane];
        #pragma unroll 1
        for (int r = 0; r < 16; ++r) {
            float v = v0; int m = m0;
            #pragma unroll
            for (int off = 1; off < 64; off <<= 1) {
                float ov = __shfl_xor(v, off, 64);
                int   om = __shfl_xor(m, off, 64);
                if (ov < v || (ov == v && om < m)) { v = ov; m = om; }
            }
            if (lane == 0) idx_out[(size_t)bn * KNN + r] = m;
            if (m0 == m) v0 = KINF;          // m0 distinct across lanes
        }
    }
}

// ---------------------------------------------------------------------------
// LayerNorm f32 in -> bf16 out
// ---------------------------------------------------------------------------
__global__ __launch_bounds__(256) void ln_kernel(const float* __restrict__ in,
                                                 const float* __restrict__ g,
                                                 const float* __restrict__ bb,
                                                 ushort* __restrict__ out) {
    int r = blockIdx.x;
    int t = threadIdx.x;
    float v = in[(size_t)r * DIM + t];

    __shared__ float sw[4];
    __shared__ float sw2[4];

    float s = v;
    #pragma unroll
    for (int off = 32; off > 0; off >>= 1) s += __shfl_down(s, off);
    if ((t & 63) == 0) sw[t >> 6] = s;
    __syncthreads();
    float mean = (sw[0] + sw[1] + sw[2] + sw[3]) * (1.0f / DIM);

    float dlt = v - mean;
    float s2 = dlt * dlt;
    #pragma unroll
    for (int off = 32; off > 0; off >>= 1) s2 += __shfl_down(s2, off);
    if ((t & 63) == 0) sw2[t >> 6] = s2;
    __syncthreads();
    float var = (sw2[0] + sw2[1] + sw2[2] + sw2[3]) * (1.0f / DIM);

    out[(size_t)r * DIM + t] = f2b(dlt * rsqrtf(var + LN_EPS) * g[t] + bb[t]);
}

// ---------------------------------------------------------------------------
// Transpose-convert: f32 in[R][C] -> bf16 out[C][R]
// ---------------------------------------------------------------------------
__global__ __launch_bounds__(256) void tconv(const float* __restrict__ in,
                                             ushort* __restrict__ out, int R, int C) {
    __shared__ float tile[32][33];
    int tx = threadIdx.x & 31, ty = threadIdx.x >> 5;   // ty 0..7
    int r0 = blockIdx.y * 32, c0 = blockIdx.x * 32;
    #pragma unroll
    for (int k = 0; k < 4; ++k)
        tile[ty + 8 * k][tx] = in[(size_t)(r0 + ty + 8 * k) * C + c0 + tx];
    __syncthreads();
    #pragma unroll
    for (int k = 0; k < 4; ++k)
        out[(size_t)(c0 + ty + 8 * k) * R + r0 + tx] = f2b(tile[tx][ty + 8 * k]);
}

// straight f32 -> bf16 (exactly n = grid*256 elements)
__global__ __launch_bounds__(256) void conv_k(const float* __restrict__ in,
                                              ushort* __restrict__ out) {
    int i = blockIdx.x * 256 + threadIdx.x;
    out[i] = f2b(in[i]);
}

// ---------------------------------------------------------------------------
// MFMA bf16 GEMM: C[M][N] = act(A[M][K] @ Bt[N][K]^T + bias) (+res)
// 128x128 tile, BK=32, 4 waves (2x2), 16x16x32 MFMA, global_load_lds staging,
// XOR-swizzled LDS (involution applied to global src so it cancels on read).
// ---------------------------------------------------------------------------
template <int ACT, int OUTBF, int RES>
__global__ __launch_bounds__(256) void gemm_bt(
    const ushort* __restrict__ A, const ushort* __restrict__ Bt,
    const float* __restrict__ bias, const float* __restrict__ res,
    void* __restrict__ Cv, int M, int N, int K)
{
    __shared__ ushort As[4096];   // [128][32] bf16, swizzled
    __shared__ ushort Bs[4096];
    const int t = threadIdx.x;
    const int wave = t >> 6, lane = t & 63;
    const int m0 = blockIdx.y * 128, n0 = blockIdx.x * 128;
    const int wr = (wave >> 1) * 64, wc = (wave & 1) * 64;

    f32x4 acc[4][4];
    #pragma unroll
    for (int i = 0; i < 4; ++i)
        #pragma unroll
        for (int j = 0; j < 4; ++j) acc[i][j] = {0.f, 0.f, 0.f, 0.f};

    // staging geometry
    const int rA0 = (wave * 2 + 0) * 16 + (lane >> 2);
    const int rA1 = (wave * 2 + 1) * 16 + (lane >> 2);
    const int u4 = lane & 3;
    const int sw0 = (rA0 + (rA0 >> 2)) & 3;
    const int sw1 = (rA1 + (rA1 >> 2)) & 3;
    char* ldsA0 = (char*)As + (wave * 2 + 0) * 1024 + lane * 16;
    char* ldsA1 = (char*)As + (wave * 2 + 1) * 1024 + lane * 16;
    char* ldsB0 = (char*)Bs + (wave * 2 + 0) * 1024 + lane * 16;
    char* ldsB1 = (char*)Bs + (wave * 2 + 1) * 1024 + lane * 16;
    const size_t aOff0 = (size_t)(m0 + rA0) * K + (size_t)((u4 ^ sw0) * 8);
    const size_t aOff1 = (size_t)(m0 + rA1) * K + (size_t)((u4 ^ sw1) * 8);
    const size_t bOff0 = (size_t)(n0 + rA0) * K + (size_t)((u4 ^ sw0) * 8);
    const size_t bOff1 = (size_t)(n0 + rA1) * K + (size_t)((u4 ^ sw1) * 8);

    const int cl = lane & 15, gq = lane >> 4;

    for (int k0 = 0; k0 < K; k0 += 32) {
        gload16(A + aOff0 + k0, ldsA0);
        gload16(A + aOff1 + k0, ldsA1);
        gload16(Bt + bOff0 + k0, ldsB0);
        gload16(Bt + bOff1 + k0, ldsB1);
        __syncthreads();

        short8 av[4], bv[4];
        #pragma unroll
        for (int mi = 0; mi < 4; ++mi) {
            int row = wr + mi * 16 + cl;
            int s = (row + (row >> 2)) & 3;
            av[mi] = *(const short8*)((const char*)As + row * 64 + ((gq ^ s) << 4));
            int rowb = wc + mi * 16 + cl;
            int sb = (rowb + (rowb >> 2)) & 3;
            bv[mi] = *(const short8*)((const char*)Bs + rowb * 64 + ((gq ^ sb) << 4));
        }
        #pragma unroll
        for (int mi = 0; mi < 4; ++mi)
            #pragma unroll
            for (int ni = 0; ni < 4; ++ni)
                acc[mi][ni] = __builtin_amdgcn_mfma_f32_16x16x32_bf16(av[mi], bv[ni], acc[mi][ni], 0, 0, 0);
        __syncthreads();
    }

    float* Cf = (float*)Cv;
    ushort* Cb = (ushort*)Cv;
    #pragma unroll
    for (int ni = 0; ni < 4; ++ni) {
        int col = n0 + wc + ni * 16 + cl;
        float bvv = bias[col];
        #pragma unroll
        for (int mi = 0; mi < 4; ++mi) {
            #pragma unroll
            for (int r = 0; r < 4; ++r) {
                int row = m0 + wr + mi * 16 + gq * 4 + r;
                float v = acc[mi][ni][r] + bvv;
                if (ACT == 1) v = gelu_f(v);
                if (RES) v += res[(size_t)row * N + col];
                if (OUTBF) Cb[(size_t)row * N + col] = f2b(v);
                else       Cf[(size_t)row * N + col] = v;
            }
        }
    }
}

// ---------------------------------------------------------------------------
// hid = gelu(rel @ W_rel1 + b_rel1) for all (point, neighbor) rows -> bf16
// ---------------------------------------------------------------------------
__global__ __launch_bounds__(256) void hid_kernel(const float* __restrict__ xyz,
                                                  const int* __restrict__ idx,
                                                  const float* __restrict__ W1,
                                                  const float* __restrict__ b1,
                                                  ushort* __restrict__ hid) {
    int t = threadIdx.x;
    int rl = t >> 6, i = t & 63;
    int row = blockIdx.x * 4 + rl;
    int bn = row >> 4;
    int b = bn >> 12;
    int n = bn & (NPTS - 1);
    int m = idx[row];
    const float* xb = xyz + (size_t)b * NPTS * 3;
    float dx = xb[m * 3 + 0] - xb[n * 3 + 0];
    float dy = xb[m * 3 + 1] - xb[n * 3 + 1];
    float dz = xb[m * 3 + 2] - xb[n * 3 + 2];
    float nr = sqrtf(dx * dx + dy * dy + dz * dz);
    float a = b1[i] + dx * W1[i] + dy * W1[64 + i] + dz * W1[128 + i] + nr * W1[192 + i];
    hid[(size_t)row * 64 + i] = f2b(gelu_f(a));
}

// ---------------------------------------------------------------------------
// Attention with factored rel_e:
//   logit_hj = ( q_h . k_j|h  +  qw_h . hid_j ) / 8       (b_rel2 cancels)
//   out_d    = sum_j p_j v_j[d] + sum_i hp_h[i] w2[i][d] + b_rel2[d]
//   qw_h[i] = sum_{d in head h} q_d w2[i][d];  hp_h[i] = sum_j p_hj hid_j[i]
// 8 points per block; wave == head; W_rel2 staged once (bf16, swizzled).
// ---------------------------------------------------------------------------
#define PTS 8
__global__ __launch_bounds__(256) void attn_kernel(
    const int* __restrict__ idx,
    const ushort* __restrict__ qb, const ushort* __restrict__ kb,
    const ushort* __restrict__ vb, const ushort* __restrict__ hidg,
    const ushort* __restrict__ w2b, const float* __restrict__ b_rel2,
    ushort* __restrict__ aob)
{
    __shared__ uint4 w2S4[2048];      // 32KB: [64 rows][32 chunks], chunk u holds global chunk u^(i&7)
    __shared__ uint4 hidS4[16 * 9];   // [16 rows][stride 144B], 8 valid chunks/row
    __shared__ float qS[256];
    __shared__ float qwS[256];
    __shared__ float psS[64];
    __shared__ float hpS[256];
    __shared__ int   nbAll[128];
    ushort* w2S = (ushort*)w2S4;
    ushort* hidS = (ushort*)hidS4;

    const int t = threadIdx.x;
    const int h = t >> 6, lane = t & 63;
    const int blk = blockIdx.x;
    const int bn0 = blk * PTS;
    const int R0 = blk * (PTS * 16);

    #pragma unroll
    for (int s = 0; s < 8; ++s) {
        int ci = t + 256 * s;            // 0..2047
        int i = ci >> 5, u = ci & 31;
        int su = u ^ (i & 7);
        w2S4[ci] = *(const uint4*)(w2b + i * 256 + su * 8);
    }
    if (t < 128) nbAll[t] = idx[R0 + t];
    __syncthreads();

    const float b2d = b_rel2[t];
    const int cd = t >> 3;               // chunk of dim d = t
    const int dlo = t & 7;

    for (int pt = 0; pt < PTS; ++pt) {
        const int bn = bn0 + pt;
        const size_t base = (size_t)(bn >> 12) * NPTS;

        qS[t] = b2f(qb[(size_t)bn * 256 + t]);
        if (t < 128) {
            int j = t >> 3, c = t & 7;
            hidS4[j * 9 + c] = *(const uint4*)(hidg + (size_t)(R0 + pt * 16 + j) * 64 + c * 8);
        }
        __syncthreads();

        // phase 1: qw[h][i]
        {
            int i = lane, si = i & 7;
            float acc = 0.f;
            #pragma unroll
            for (int cc = 0; cc < 8; ++cc) {
                int gc = cc ^ si;                        // global chunk within head
                uint4 w = w2S4[i * 32 + h * 8 + cc];     // holds global chunk h*8+gc
                acc += dot8(w, &qS[h * 64 + gc * 8]);
            }
            qwS[t] = acc;
        }
        __syncthreads();

        // phase 2: logits + softmax (wave h = head h; lane = j*4+sub)
        {
            int j = lane >> 2, sub = lane & 3;
            int m = nbAll[pt * 16 + j];
            const ushort* krow = kb + (base + m) * 256 + h * 64 + sub * 16;
            uint4 ka = *(const uint4*)krow;
            uint4 kc = *(const uint4*)(krow + 8);
            const float* qp = &qS[h * 64 + sub * 16];
            float d1 = dot8(ka, qp) + dot8(kc, qp + 8);
            const ushort* hrow = hidS + j * 72 + sub * 16;
            uint4 ha = *(const uint4*)hrow;
            uint4 hc = *(const uint4*)(hrow + 8);
            const float* qwp = &qwS[h * 64 + sub * 16];
            float d2 = dot8(ha, qwp) + dot8(hc, qwp + 8);
            float pp = d1 + d2;
            pp += __shfl_xor(pp, 1, 64);
            pp += __shfl_xor(pp, 2, 64);
            pp *= 0.125f;
            float mx = pp;
            mx = fmaxf(mx, __shfl_xor(mx, 4, 64));
            mx = fmaxf(mx, __shfl_xor(mx, 8, 64));
            mx = fmaxf(mx, __shfl_xor(mx, 16, 64));
            mx = fmaxf(mx, __shfl_xor(mx, 32, 64));
            float e = expf(pp - mx);
            float ss = e;
            ss += __shfl_xor(ss, 4, 64);
            ss += __shfl_xor(ss, 8, 64);
            ss += __shfl_xor(ss, 16, 64);
            ss += __shfl_xor(ss, 32, 64);       // = sum_j e_j (bits 2..5 = full j range)
            float pj = e / ss;
            if (sub == 0) psS[h * 16 + j] = pj;
        }
        __syncthreads();

        // phase 3a: hp[h][i]
        {
            int i = lane;
            float acc = 0.f;
            #pragma unroll
            for (int j = 0; j < 16; ++j)
                acc += psS[h * 16 + j] * b2f(hidS[j * 72 + i]);
            hpS[t] = acc;
        }
        __syncthreads();

        // phase 3b: output dim d = t
        {
            float o = b2d;
            #pragma unroll
            for (int j = 0; j < 16; ++j) {
                int m = nbAll[pt * 16 + j];
                o += psS[h * 16 + j] * b2f(vb[(base + m) * 256 + t]);
            }
            #pragma unroll
            for (int i = 0; i < 64; ++i) {
                int u = cd ^ (i & 7);
                float wv = b2f(w2S[i * 256 + u * 8 + dlo]);
                o += hpS[h * 64 + i] * wv;
            }
            aob[(size_t)bn * 256 + t] = f2b(o);
        }
        __syncthreads();
    }
}

// ---------------------------------------------------------------------------
extern "C" void kernel_launch(void* const* d_in, const int* in_sizes, int n_in,
                              void* d_out, int out_size, void* d_ws, size_t ws_size,
                              hipStream_t stream) {
    const float* xyz    = (const float*)d_in[0];
    const float* feats  = (const float*)d_in[1];
    const float* ln_q_g = (const float*)d_in[2];
    const float* ln_q_b = (const float*)d_in[3];
    const float* Wq     = (const float*)d_in[4];
    const float* bq     = (const float*)d_in[5];
    const float* Wk     = (const float*)d_in[6];
    const float* bk     = (const float*)d_in[7];
    const float* Wv     = (const float*)d_in[8];
    const float* bv     = (const float*)d_in[9];
    const float* W_rel1 = (const float*)d_in[10];
    const float* b_rel1 = (const float*)d_in[11];
    const float* W_rel2 = (const float*)d_in[12];
    const float* b_rel2 = (const float*)d_in[13];
    const float* Wo     = (const float*)d_in[14];
    const float* bo     = (const float*)d_in[15];
    const float* ln_f_g = (const float*)d_in[16];
    const float* ln_f_b = (const float*)d_in[17];
    const float* W_ff1  = (const float*)d_in[18];
    const float* b_ff1  = (const float*)d_in[19];
    const float* W_ff2  = (const float*)d_in[20];
    const float* b_ff2  = (const float*)d_in[21];
    (void)in_sizes; (void)n_in; (void)out_size; (void)ws_size;

    char* ws = (char*)d_ws;
    const size_t MB = 1u << 20;
    int*    idx    = (int*)ws;                       // 1 MB
    ushort* xb     = (ushort*)(ws + 1 * MB);         // 8 MB  (LN out; reused as attn out)
    ushort* qb     = (ushort*)(ws + 9 * MB);         // 8 MB  (q; reused as h)
    ushort* kb     = (ushort*)(ws + 17 * MB);        // 8 MB
    ushort* vb     = (ushort*)(ws + 25 * MB);        // 8 MB
    ushort* hidg   = (ushort*)(ws + 33 * MB);        // 32 MB (hid; reused as ff1 out)
    float*  feats1 = (float*)(ws + 65 * MB);         // 16 MB
    ushort* WqT    = (ushort*)(ws + 81 * MB);
    ushort* WkT    = WqT + 65536;
    ushort* WvT    = WkT + 65536;
    ushort* WoT    = WvT + 65536;
    ushort* Wf1T   = WoT + 65536;                    // [1024][256]
    ushort* Wf2T   = Wf1T + 262144;                  // [256][1024]
    ushort* w2b    = Wf2T + 262144;                  // [64][256]
    ushort* aob  = xb;
    ushort* hb   = qb;
    ushort* ff1b = hidg;

    tconv<<<dim3(8, 8),  256, 0, stream>>>(Wq, WqT, 256, 256);
    tconv<<<dim3(8, 8),  256, 0, stream>>>(Wk, WkT, 256, 256);
    tconv<<<dim3(8, 8),  256, 0, stream>>>(Wv, WvT, 256, 256);
    tconv<<<dim3(8, 8),  256, 0, stream>>>(Wo, WoT, 256, 256);
    tconv<<<dim3(32, 8), 256, 0, stream>>>(W_ff1, Wf1T, 256, 1024);
    tconv<<<dim3(8, 32), 256, 0, stream>>>(W_ff2, Wf2T, 1024, 256);
    conv_k<<<64, 256, 0, stream>>>(W_rel2, w2b);

    knn_kernel<<<MTOT, 256, 0, stream>>>(xyz, idx);
    ln_kernel<<<MTOT, 256, 0, stream>>>(feats, ln_q_g, ln_q_b, xb);

    gemm_bt<0, 1, 0><<<dim3(2, 128), 256, 0, stream>>>(xb, WqT, bq, nullptr, qb, MTOT, 256, 256);
    gemm_bt<0, 1, 0><<<dim3(2, 128), 256, 0, stream>>>(xb, WkT, bk, nullptr, kb, MTOT, 256, 256);
    gemm_bt<0, 1, 0><<<dim3(2, 128), 256, 0, stream>>>(xb, WvT, bv, nullptr, vb, MTOT, 256, 256);

    hid_kernel<<<MTOT * 16 / 4, 256, 0, stream>>>(xyz, idx, W_rel1, b_rel1, hidg);
    attn_kernel<<<MTOT / PTS, 256, 0, stream>>>(idx, qb, kb, vb, hidg, w2b, b_rel2, aob);

    // feats1 = attn_out @ Wo + bo + feats
    gemm_bt<0, 0, 1><<<dim3(2, 128), 256, 0, stream>>>(aob, WoT, bo, feats, feats1, MTOT, 256, 256);
    ln_kernel<<<MTOT, 256, 0, stream>>>(feats1, ln_f_g, ln_f_b, hb);
    // ff1 = gelu(h @ W_ff1 + b_ff1)  (bf16)
    gemm_bt<1, 1, 0><<<dim3(8, 128), 256, 0, stream>>>(hb, Wf1T, b_ff1, nullptr, ff1b, MTOT, 1024, 256);
    // out = ff1 @ W_ff2 + b_ff2 + feats1
    gemm_bt<0, 0, 1><<<dim3(2, 128), 256, 0, stream>>>(ff1b, Wf2T, b_ff2, feats1, (float*)d_out, MTOT, 256, 1024);
}

// Round 5
// 403.756 us; speedup vs baseline: 4.5968x; 1.4040x over previous
//
#include <hip/hip_runtime.h>
#include <hip/hip_bf16.h>
#include <math.h>

#define NB 4
#define NPTS 4096
#define DIM 256
#define KNN 16
#define HID 64
#define FFDIM 1024
#define LN_EPS 1e-5f
#define MTOT (NB * NPTS)
#define KINF 3e38f

typedef __attribute__((ext_vector_type(8))) short short8;
typedef __attribute__((ext_vector_type(4))) float f32x4;

__device__ __forceinline__ float gelu_f(float x) {
    return 0.5f * x * (1.0f + erff(x * 0.7071067811865476f));
}
__device__ __forceinline__ float b2f(ushort u) {
    return __uint_as_float(((unsigned)u) << 16);
}
__device__ __forceinline__ ushort f2b(float f) {
    unsigned u = __float_as_uint(f);
    return (ushort)((u + 0x7fffu + ((u >> 16) & 1u)) >> 16);
}
__device__ __forceinline__ void gload16(const void* g, void* l) {
    __builtin_amdgcn_global_load_lds((const __attribute__((address_space(1))) void*)g,
                                     (__attribute__((address_space(3))) void*)l, 16, 0, 0);
}
// dot of 8 bf16 (packed in uint4) with 8 consecutive f32
__device__ __forceinline__ float dot8(uint4 w, const float* q) {
    float s = 0.f;
    s += b2f((ushort)(w.x & 0xffff)) * q[0]; s += b2f((ushort)(w.x >> 16)) * q[1];
    s += b2f((ushort)(w.y & 0xffff)) * q[2]; s += b2f((ushort)(w.y >> 16)) * q[3];
    s += b2f((ushort)(w.z & 0xffff)) * q[4]; s += b2f((ushort)(w.z >> 16)) * q[5];
    s += b2f((ushort)(w.w & 0xffff)) * q[6]; s += b2f((ushort)(w.w >> 16)) * q[7];
    return s;
}
// monotone 10-bit radix key for positive f32 (sign -> bin 0)
__device__ __forceinline__ int rkey(float f) {
    unsigned u = __float_as_uint(f);
    int k = (int)(u >> 21);
    if (u >> 31) k = 0;
    return k > 1023 ? 1023 : k;
}

// ---------------------------------------------------------------------------
// KNN v3: one block per query; distances in registers; radix histogram
// (1024 quarter-octave bins) -> threshold bin T; compact (key<=T) candidates
// (~20, cap 64) to LDS; wave 0 bitonic-sorts 64 lexicographic (d, idx) pairs.
// ---------------------------------------------------------------------------
__global__ __launch_bounds__(256) void knn_kernel(const float* __restrict__ xyz,
                                                  int* __restrict__ idx_out) {
    int bn = blockIdx.x;
    int b = bn >> 12;
    int n = bn & (NPTS - 1);
    const float* base = xyz + (size_t)b * NPTS * 3;
    int t = threadIdx.x;
    int lane = t & 63, wv = t >> 6;

    __shared__ int hist[1024];
    __shared__ int wsum[4];
    __shared__ int binT;
    __shared__ int cntC;
    __shared__ float lv[64];
    __shared__ int   li[64];

    hist[t] = 0; hist[t + 256] = 0; hist[t + 512] = 0; hist[t + 768] = 0;
    if (t == 0) cntC = 0;

    float qx = base[n * 3 + 0], qy = base[n * 3 + 1], qz = base[n * 3 + 2];
    float sqn = qx * qx + qy * qy + qz * qz;

    float d[16];
    #pragma unroll
    for (int i = 0; i < 16; ++i) {
        int m = t + 256 * i;
        float x = base[m * 3 + 0], y = base[m * 3 + 1], z = base[m * 3 + 2];
        float sqm = x * x + y * y + z * z;
        float dot = qx * x + qy * y + qz * z;
        float dd = sqn + sqm - 2.0f * dot;
        d[i] = (m == n) ? KINF : dd;
    }
    __syncthreads();

    #pragma unroll
    for (int i = 0; i < 16; ++i) atomicAdd(&hist[rkey(d[i])], 1);
    __syncthreads();

    // block scan over 1024 bins (4 per thread)
    int h0 = hist[4 * t], h1 = hist[4 * t + 1], h2 = hist[4 * t + 2], h3 = hist[4 * t + 3];
    int s = h0 + h1 + h2 + h3;
    int inc = s;
    #pragma unroll
    for (int off = 1; off < 64; off <<= 1) {
        int o = __shfl_up(inc, off, 64);
        if (lane >= off) inc += o;
    }
    if (lane == 63) wsum[wv] = inc;
    __syncthreads();
    int woff = 0;
    if (wv > 0) woff += wsum[0];
    if (wv > 1) woff += wsum[1];
    if (wv > 2) woff += wsum[2];
    int excl = woff + inc - s;
    if (excl < KNN && excl + s >= KNN) {
        int c = excl;
        int hh[4] = {h0, h1, h2, h3};
        int T = 4 * t;
        #pragma unroll
        for (int j = 0; j < 4; ++j) {
            if (c < KNN && c + hh[j] >= KNN) T = 4 * t + j;
            c += hh[j];
        }
        binT = T;
    }
    __syncthreads();

    int T = binT;
    #pragma unroll
    for (int i = 0; i < 16; ++i) {
        if (rkey(d[i]) <= T) {
            int pos = atomicAdd(&cntC, 1);
            if (pos < 64) { lv[pos] = d[i]; li[pos] = t + 256 * i; }
        }
    }
    __syncthreads();

    if (t < 64) {
        int nc = cntC; nc = nc > 64 ? 64 : nc;
        float v = (t < nc) ? lv[t] : KINF;
        int   m = (t < nc) ? li[t] : 0x7fffffff;
        #pragma unroll
        for (int k = 2; k <= 64; k <<= 1) {
            #pragma unroll
            for (int j = 32; j > 0; j >>= 1) {
                if (j < k) {
                    float ov = __shfl_xor(v, j, 64);
                    int   om = __shfl_xor(m, j, 64);
                    bool keepMin = ((lane & k) == 0) == ((lane & j) == 0);
                    bool less = (ov < v) || (ov == v && om < m);
                    if (keepMin == less) { v = ov; m = om; }
                }
            }
        }
        if (t < KNN) idx_out[(size_t)bn * KNN + t] = m;
    }
}

// ---------------------------------------------------------------------------
// LayerNorm f32 in -> bf16 out
// ---------------------------------------------------------------------------
__global__ __launch_bounds__(256) void ln_kernel(const float* __restrict__ in,
                                                 const float* __restrict__ g,
                                                 const float* __restrict__ bb,
                                                 ushort* __restrict__ out) {
    int r = blockIdx.x;
    int t = threadIdx.x;
    float v = in[(size_t)r * DIM + t];

    __shared__ float sw[4];
    __shared__ float sw2[4];

    float s = v;
    #pragma unroll
    for (int off = 32; off > 0; off >>= 1) s += __shfl_down(s, off);
    if ((t & 63) == 0) sw[t >> 6] = s;
    __syncthreads();
    float mean = (sw[0] + sw[1] + sw[2] + sw[3]) * (1.0f / DIM);

    float dlt = v - mean;
    float s2 = dlt * dlt;
    #pragma unroll
    for (int off = 32; off > 0; off >>= 1) s2 += __shfl_down(s2, off);
    if ((t & 63) == 0) sw2[t >> 6] = s2;
    __syncthreads();
    float var = (sw2[0] + sw2[1] + sw2[2] + sw2[3]) * (1.0f / DIM);

    out[(size_t)r * DIM + t] = f2b(dlt * rsqrtf(var + LN_EPS) * g[t] + bb[t]);
}

// ---------------------------------------------------------------------------
// Transpose-convert: f32 in[R][C] -> bf16 out[C][R]
// ---------------------------------------------------------------------------
__global__ __launch_bounds__(256) void tconv(const float* __restrict__ in,
                                             ushort* __restrict__ out, int R, int C) {
    __shared__ float tile[32][33];
    int tx = threadIdx.x & 31, ty = threadIdx.x >> 5;   // ty 0..7
    int r0 = blockIdx.y * 32, c0 = blockIdx.x * 32;
    #pragma unroll
    for (int k = 0; k < 4; ++k)
        tile[ty + 8 * k][tx] = in[(size_t)(r0 + ty + 8 * k) * C + c0 + tx];
    __syncthreads();
    #pragma unroll
    for (int k = 0; k < 4; ++k)
        out[(size_t)(c0 + ty + 8 * k) * R + r0 + tx] = f2b(tile[tx][ty + 8 * k]);
}

// straight f32 -> bf16 (exactly n = grid*256 elements)
__global__ __launch_bounds__(256) void conv_k(const float* __restrict__ in,
                                              ushort* __restrict__ out) {
    int i = blockIdx.x * 256 + threadIdx.x;
    out[i] = f2b(in[i]);
}

// ---------------------------------------------------------------------------
// MFMA bf16 GEMM: C[M][N] = act(A[M][K] @ Bt[N][K]^T + bias) (+res)
// 128x128 tile, BK=32, 4 waves (2x2), 16x16x32 MFMA, global_load_lds staging,
// XOR-swizzled LDS (involution applied to global src so it cancels on read).
// ---------------------------------------------------------------------------
template <int ACT, int OUTBF, int RES>
__global__ __launch_bounds__(256) void gemm_bt(
    const ushort* __restrict__ A, const ushort* __restrict__ Bt,
    const float* __restrict__ bias, const float* __restrict__ res,
    void* __restrict__ Cv, int M, int N, int K)
{
    __shared__ ushort As[4096];   // [128][32] bf16, swizzled
    __shared__ ushort Bs[4096];
    const int t = threadIdx.x;
    const int wave = t >> 6, lane = t & 63;
    const int m0 = blockIdx.y * 128, n0 = blockIdx.x * 128;
    const int wr = (wave >> 1) * 64, wc = (wave & 1) * 64;

    f32x4 acc[4][4];
    #pragma unroll
    for (int i = 0; i < 4; ++i)
        #pragma unroll
        for (int j = 0; j < 4; ++j) acc[i][j] = {0.f, 0.f, 0.f, 0.f};

    // staging geometry
    const int rA0 = (wave * 2 + 0) * 16 + (lane >> 2);
    const int rA1 = (wave * 2 + 1) * 16 + (lane >> 2);
    const int u4 = lane & 3;
    const int sw0 = (rA0 + (rA0 >> 2)) & 3;
    const int sw1 = (rA1 + (rA1 >> 2)) & 3;
    char* ldsA0 = (char*)As + (wave * 2 + 0) * 1024 + lane * 16;
    char* ldsA1 = (char*)As + (wave * 2 + 1) * 1024 + lane * 16;
    char* ldsB0 = (char*)Bs + (wave * 2 + 0) * 1024 + lane * 16;
    char* ldsB1 = (char*)Bs + (wave * 2 + 1) * 1024 + lane * 16;
    const size_t aOff0 = (size_t)(m0 + rA0) * K + (size_t)((u4 ^ sw0) * 8);
    const size_t aOff1 = (size_t)(m0 + rA1) * K + (size_t)((u4 ^ sw1) * 8);
    const size_t bOff0 = (size_t)(n0 + rA0) * K + (size_t)((u4 ^ sw0) * 8);
    const size_t bOff1 = (size_t)(n0 + rA1) * K + (size_t)((u4 ^ sw1) * 8);

    const int cl = lane & 15, gq = lane >> 4;

    for (int k0 = 0; k0 < K; k0 += 32) {
        gload16(A + aOff0 + k0, ldsA0);
        gload16(A + aOff1 + k0, ldsA1);
        gload16(Bt + bOff0 + k0, ldsB0);
        gload16(Bt + bOff1 + k0, ldsB1);
        __syncthreads();

        short8 av[4], bv[4];
        #pragma unroll
        for (int mi = 0; mi < 4; ++mi) {
            int row = wr + mi * 16 + cl;
            int s = (row + (row >> 2)) & 3;
            av[mi] = *(const short8*)((const char*)As + row * 64 + ((gq ^ s) << 4));
            int rowb = wc + mi * 16 + cl;
            int sb = (rowb + (rowb >> 2)) & 3;
            bv[mi] = *(const short8*)((const char*)Bs + rowb * 64 + ((gq ^ sb) << 4));
        }
        #pragma unroll
        for (int mi = 0; mi < 4; ++mi)
            #pragma unroll
            for (int ni = 0; ni < 4; ++ni)
                acc[mi][ni] = __builtin_amdgcn_mfma_f32_16x16x32_bf16(av[mi], bv[ni], acc[mi][ni], 0, 0, 0);
        __syncthreads();
    }

    float* Cf = (float*)Cv;
    ushort* Cb = (ushort*)Cv;
    #pragma unroll
    for (int ni = 0; ni < 4; ++ni) {
        int col = n0 + wc + ni * 16 + cl;
        float bvv = bias[col];
        #pragma unroll
        for (int mi = 0; mi < 4; ++mi) {
            #pragma unroll
            for (int r = 0; r < 4; ++r) {
                int row = m0 + wr + mi * 16 + gq * 4 + r;
                float v = acc[mi][ni][r] + bvv;
                if (ACT == 1) v = gelu_f(v);
                if (RES) v += res[(size_t)row * N + col];
                if (OUTBF) Cb[(size_t)row * N + col] = f2b(v);
                else       Cf[(size_t)row * N + col] = v;
            }
        }
    }
}

// ---------------------------------------------------------------------------
// hid = gelu(rel @ W_rel1 + b_rel1) for all (point, neighbor) rows -> bf16
// ---------------------------------------------------------------------------
__global__ __launch_bounds__(256) void hid_kernel(const float* __restrict__ xyz,
                                                  const int* __restrict__ idx,
                                                  const float* __restrict__ W1,
                                                  const float* __restrict__ b1,
                                                  ushort* __restrict__ hid) {
    int t = threadIdx.x;
    int rl = t >> 6, i = t & 63;
    int row = blockIdx.x * 4 + rl;
    int bn = row >> 4;
    int b = bn >> 12;
    int n = bn & (NPTS - 1);
    int m = idx[row];
    const float* xb = xyz + (size_t)b * NPTS * 3;
    float dx = xb[m * 3 + 0] - xb[n * 3 + 0];
    float dy = xb[m * 3 + 1] - xb[n * 3 + 1];
    float dz = xb[m * 3 + 2] - xb[n * 3 + 2];
    float nr = sqrtf(dx * dx + dy * dy + dz * dz);
    float a = b1[i] + dx * W1[i] + dy * W1[64 + i] + dz * W1[128 + i] + nr * W1[192 + i];
    hid[(size_t)row * 64 + i] = f2b(gelu_f(a));
}

// ---------------------------------------------------------------------------
// Attention with factored rel_e:
//   logit_hj = ( q_h . k_j|h  +  qw_h . hid_j ) / 8       (b_rel2 cancels)
//   out_d    = sum_j p_j v_j[d] + sum_i hp_h[i] w2[i][d] + b_rel2[d]
//   qw_h[i] = sum_{d in head h} q_d w2[i][d];  hp_h[i] = sum_j p_hj hid_j[i]
// 8 points per block; wave == head; W_rel2 staged once (bf16, swizzled).
// ---------------------------------------------------------------------------
#define PTS 8
__global__ __launch_bounds__(256) void attn_kernel(
    const int* __restrict__ idx,
    const ushort* __restrict__ qb, const ushort* __restrict__ kb,
    const ushort* __restrict__ vb, const ushort* __restrict__ hidg,
    const ushort* __restrict__ w2b, const float* __restrict__ b_rel2,
    ushort* __restrict__ aob)
{
    __shared__ uint4 w2S4[2048];      // 32KB: [64 rows][32 chunks], chunk u holds global chunk u^(i&7)
    __shared__ uint4 hidS4[16 * 9];   // [16 rows][stride 144B], 8 valid chunks/row
    __shared__ float qS[256];
    __shared__ float qwS[256];
    __shared__ float psS[64];
    __shared__ float hpS[256];
    __shared__ int   nbAll[128];
    ushort* w2S = (ushort*)w2S4;
    ushort* hidS = (ushort*)hidS4;

    const int t = threadIdx.x;
    const int h = t >> 6, lane = t & 63;
    const int blk = blockIdx.x;
    const int bn0 = blk * PTS;
    const int R0 = blk * (PTS * 16);

    #pragma unroll
    for (int s = 0; s < 8; ++s) {
        int ci = t + 256 * s;            // 0..2047
        int i = ci >> 5, u = ci & 31;
        int su = u ^ (i & 7);
        w2S4[ci] = *(const uint4*)(w2b + i * 256 + su * 8);
    }
    if (t < 128) nbAll[t] = idx[R0 + t];
    __syncthreads();

    const float b2d = b_rel2[t];
    const int cd = t >> 3;               // chunk of dim d = t
    const int dlo = t & 7;

    for (int pt = 0; pt < PTS; ++pt) {
        const int bn = bn0 + pt;
        const size_t base = (size_t)(bn >> 12) * NPTS;

        qS[t] = b2f(qb[(size_t)bn * 256 + t]);
        if (t < 128) {
            int j = t >> 3, c = t & 7;
            hidS4[j * 9 + c] = *(const uint4*)(hidg + (size_t)(R0 + pt * 16 + j) * 64 + c * 8);
        }
        __syncthreads();

        // phase 1: qw[h][i]
        {
            int i = lane, si = i & 7;
            float acc = 0.f;
            #pragma unroll
            for (int cc = 0; cc < 8; ++cc) {
                int gc = cc ^ si;                        // global chunk within head
                uint4 w = w2S4[i * 32 + h * 8 + cc];     // holds global chunk h*8+gc
                acc += dot8(w, &qS[h * 64 + gc * 8]);
            }
            qwS[t] = acc;
        }
        __syncthreads();

        // phase 2: logits + softmax (wave h = head h; lane = j*4+sub)
        {
            int j = lane >> 2, sub = lane & 3;
            int m = nbAll[pt * 16 + j];
            const ushort* krow = kb + (base + m) * 256 + h * 64 + sub * 16;
            uint4 ka = *(const uint4*)krow;
            uint4 kc = *(const uint4*)(krow + 8);
            const float* qp = &qS[h * 64 + sub * 16];
            float d1 = dot8(ka, qp) + dot8(kc, qp + 8);
            const ushort* hrow = hidS + j * 72 + sub * 16;
            uint4 ha = *(const uint4*)hrow;
            uint4 hc = *(const uint4*)(hrow + 8);
            const float* qwp = &qwS[h * 64 + sub * 16];
            float d2 = dot8(ha, qwp) + dot8(hc, qwp + 8);
            float pp = d1 + d2;
            pp += __shfl_xor(pp, 1, 64);
            pp += __shfl_xor(pp, 2, 64);
            pp *= 0.125f;
            float mx = pp;
            mx = fmaxf(mx, __shfl_xor(mx, 4, 64));
            mx = fmaxf(mx, __shfl_xor(mx, 8, 64));
            mx = fmaxf(mx, __shfl_xor(mx, 16, 64));
            mx = fmaxf(mx, __shfl_xor(mx, 32, 64));
            float e = expf(pp - mx);
            float ss = e;
            ss += __shfl_xor(ss, 4, 64);
            ss += __shfl_xor(ss, 8, 64);
            ss += __shfl_xor(ss, 16, 64);
            ss += __shfl_xor(ss, 32, 64);       // = sum_j e_j (bits 2..5 = full j range)
            float pj = e / ss;
            if (sub == 0) psS[h * 16 + j] = pj;
        }
        __syncthreads();

        // phase 3a: hp[h][i]
        {
            int i = lane;
            float acc = 0.f;
            #pragma unroll
            for (int j = 0; j < 16; ++j)
                acc += psS[h * 16 + j] * b2f(hidS[j * 72 + i]);
            hpS[t] = acc;
        }
        __syncthreads();

        // phase 3b: output dim d = t
        {
            float o = b2d;
            #pragma unroll
            for (int j = 0; j < 16; ++j) {
                int m = nbAll[pt * 16 + j];
                o += psS[h * 16 + j] * b2f(vb[(base + m) * 256 + t]);
            }
            #pragma unroll
            for (int i = 0; i < 64; ++i) {
                int u = cd ^ (i & 7);
                float wv = b2f(w2S[i * 256 + u * 8 + dlo]);
                o += hpS[h * 64 + i] * wv;
            }
            aob[(size_t)bn * 256 + t] = f2b(o);
        }
        __syncthreads();
    }
}

// ---------------------------------------------------------------------------
extern "C" void kernel_launch(void* const* d_in, const int* in_sizes, int n_in,
                              void* d_out, int out_size, void* d_ws, size_t ws_size,
                              hipStream_t stream) {
    const float* xyz    = (const float*)d_in[0];
    const float* feats  = (const float*)d_in[1];
    const float* ln_q_g = (const float*)d_in[2];
    const float* ln_q_b = (const float*)d_in[3];
    const float* Wq     = (const float*)d_in[4];
    const float* bq     = (const float*)d_in[5];
    const float* Wk     = (const float*)d_in[6];
    const float* bk     = (const float*)d_in[7];
    const float* Wv     = (const float*)d_in[8];
    const float* bv     = (const float*)d_in[9];
    const float* W_rel1 = (const float*)d_in[10];
    const float* b_rel1 = (const float*)d_in[11];
    const float* W_rel2 = (const float*)d_in[12];
    const float* b_rel2 = (const float*)d_in[13];
    const float* Wo     = (const float*)d_in[14];
    const float* bo     = (const float*)d_in[15];
    const float* ln_f_g = (const float*)d_in[16];
    const float* ln_f_b = (const float*)d_in[17];
    const float* W_ff1  = (const float*)d_in[18];
    const float* b_ff1  = (const float*)d_in[19];
    const float* W_ff2  = (const float*)d_in[20];
    const float* b_ff2  = (const float*)d_in[21];
    (void)in_sizes; (void)n_in; (void)out_size; (void)ws_size;

    char* ws = (char*)d_ws;
    const size_t MB = 1u << 20;
    int*    idx    = (int*)ws;                       // 1 MB
    ushort* xb     = (ushort*)(ws + 1 * MB);         // 8 MB  (LN out; reused as attn out)
    ushort* qb     = (ushort*)(ws + 9 * MB);         // 8 MB  (q; reused as h)
    ushort* kb     = (ushort*)(ws + 17 * MB);        // 8 MB
    ushort* vb     = (ushort*)(ws + 25 * MB);        // 8 MB
    ushort* hidg   = (ushort*)(ws + 33 * MB);        // 32 MB (hid; reused as ff1 out)
    float*  feats1 = (float*)(ws + 65 * MB);         // 16 MB
    ushort* WqT    = (ushort*)(ws + 81 * MB);
    ushort* WkT    = WqT + 65536;
    ushort* WvT    = WkT + 65536;
    ushort* WoT    = WvT + 65536;
    ushort* Wf1T   = WoT + 65536;                    // [1024][256]
    ushort* Wf2T   = Wf1T + 262144;                  // [256][1024]
    ushort* w2b    = Wf2T + 262144;                  // [64][256]
    ushort* aob  = xb;
    ushort* hb   = qb;
    ushort* ff1b = hidg;

    tconv<<<dim3(8, 8),  256, 0, stream>>>(Wq, WqT, 256, 256);
    tconv<<<dim3(8, 8),  256, 0, stream>>>(Wk, WkT, 256, 256);
    tconv<<<dim3(8, 8),  256, 0, stream>>>(Wv, WvT, 256, 256);
    tconv<<<dim3(8, 8),  256, 0, stream>>>(Wo, WoT, 256, 256);
    tconv<<<dim3(32, 8), 256, 0, stream>>>(W_ff1, Wf1T, 256, 1024);
    tconv<<<dim3(8, 32), 256, 0, stream>>>(W_ff2, Wf2T, 1024, 256);
    conv_k<<<64, 256, 0, stream>>>(W_rel2, w2b);

    knn_kernel<<<MTOT, 256, 0, stream>>>(xyz, idx);
    ln_kernel<<<MTOT, 256, 0, stream>>>(feats, ln_q_g, ln_q_b, xb);

    gemm_bt<0, 1, 0><<<dim3(2, 128), 256, 0, stream>>>(xb, WqT, bq, nullptr, qb, MTOT, 256, 256);
    gemm_bt<0, 1, 0><<<dim3(2, 128), 256, 0, stream>>>(xb, WkT, bk, nullptr, kb, MTOT, 256, 256);
    gemm_bt<0, 1, 0><<<dim3(2, 128), 256, 0, stream>>>(xb, WvT, bv, nullptr, vb, MTOT, 256, 256);

    hid_kernel<<<MTOT * 16 / 4, 256, 0, stream>>>(xyz, idx, W_rel1, b_rel1, hidg);
    attn_kernel<<<MTOT / PTS, 256, 0, stream>>>(idx, qb, kb, vb, hidg, w2b, b_rel2, aob);

    // feats1 = attn_out @ Wo + bo + feats
    gemm_bt<0, 0, 1><<<dim3(2, 128), 256, 0, stream>>>(aob, WoT, bo, feats, feats1, MTOT, 256, 256);
    ln_kernel<<<MTOT, 256, 0, stream>>>(feats1, ln_f_g, ln_f_b, hb);
    // ff1 = gelu(h @ W_ff1 + b_ff1)  (bf16)
    gemm_bt<1, 1, 0><<<dim3(8, 128), 256, 0, stream>>>(hb, Wf1T, b_ff1, nullptr, ff1b, MTOT, 1024, 256);
    // out = ff1 @ W_ff2 + b_ff2 + feats1
    gemm_bt<0, 0, 1><<<dim3(2, 128), 256, 0, stream>>>(ff1b, Wf2T, b_ff2, feats1, (float*)d_out, MTOT, 256, 1024);
}

// Round 6
// 369.940 us; speedup vs baseline: 5.0170x; 1.0914x over previous
//
#include <hip/hip_runtime.h>
#include <hip/hip_bf16.h>
#include <math.h>

#define NB 4
#define NPTS 4096
#define DIM 256
#define KNN 16
#define HID 64
#define FFDIM 1024
#define LN_EPS 1e-5f
#define MTOT (NB * NPTS)
#define KINF 3e38f

typedef __attribute__((ext_vector_type(8))) short short8;
typedef __attribute__((ext_vector_type(4))) float f32x4;

__device__ __forceinline__ float gelu_f(float x) {
    return 0.5f * x * (1.0f + erff(x * 0.7071067811865476f));
}
__device__ __forceinline__ float b2f(ushort u) {
    return __uint_as_float(((unsigned)u) << 16);
}
__device__ __forceinline__ ushort f2b(float f) {
    unsigned u = __float_as_uint(f);
    return (ushort)((u + 0x7fffu + ((u >> 16) & 1u)) >> 16);
}
__device__ __forceinline__ void gload16(const void* g, void* l) {
    __builtin_amdgcn_global_load_lds((const __attribute__((address_space(1))) void*)g,
                                     (__attribute__((address_space(3))) void*)l, 16, 0, 0);
}
// dot of 8 bf16 (packed in uint4) with 8 consecutive f32
__device__ __forceinline__ float dot8(uint4 w, const float* q) {
    float s = 0.f;
    s += b2f((ushort)(w.x & 0xffff)) * q[0]; s += b2f((ushort)(w.x >> 16)) * q[1];
    s += b2f((ushort)(w.y & 0xffff)) * q[2]; s += b2f((ushort)(w.y >> 16)) * q[3];
    s += b2f((ushort)(w.z & 0xffff)) * q[4]; s += b2f((ushort)(w.z >> 16)) * q[5];
    s += b2f((ushort)(w.w & 0xffff)) * q[6]; s += b2f((ushort)(w.w >> 16)) * q[7];
    return s;
}
// monotone 10-bit radix key for positive f32 (sign -> bin 0)
__device__ __forceinline__ int rkey(float f) {
    unsigned u = __float_as_uint(f);
    int k = (int)(u >> 21);
    if (u >> 31) k = 0;
    return k > 1023 ? 1023 : k;
}

// ---------------------------------------------------------------------------
// KNN v3 (validated round 5)
// ---------------------------------------------------------------------------
__global__ __launch_bounds__(256) void knn_kernel(const float* __restrict__ xyz,
                                                  int* __restrict__ idx_out) {
    int bn = blockIdx.x;
    int b = bn >> 12;
    int n = bn & (NPTS - 1);
    const float* base = xyz + (size_t)b * NPTS * 3;
    int t = threadIdx.x;
    int lane = t & 63, wv = t >> 6;

    __shared__ int hist[1024];
    __shared__ int wsum[4];
    __shared__ int binT;
    __shared__ int cntC;
    __shared__ float lv[64];
    __shared__ int   li[64];

    hist[t] = 0; hist[t + 256] = 0; hist[t + 512] = 0; hist[t + 768] = 0;
    if (t == 0) cntC = 0;

    float qx = base[n * 3 + 0], qy = base[n * 3 + 1], qz = base[n * 3 + 2];
    float sqn = qx * qx + qy * qy + qz * qz;

    float d[16];
    #pragma unroll
    for (int i = 0; i < 16; ++i) {
        int m = t + 256 * i;
        float x = base[m * 3 + 0], y = base[m * 3 + 1], z = base[m * 3 + 2];
        float sqm = x * x + y * y + z * z;
        float dot = qx * x + qy * y + qz * z;
        float dd = sqn + sqm - 2.0f * dot;
        d[i] = (m == n) ? KINF : dd;
    }
    __syncthreads();

    #pragma unroll
    for (int i = 0; i < 16; ++i) atomicAdd(&hist[rkey(d[i])], 1);
    __syncthreads();

    int h0 = hist[4 * t], h1 = hist[4 * t + 1], h2 = hist[4 * t + 2], h3 = hist[4 * t + 3];
    int s = h0 + h1 + h2 + h3;
    int inc = s;
    #pragma unroll
    for (int off = 1; off < 64; off <<= 1) {
        int o = __shfl_up(inc, off, 64);
        if (lane >= off) inc += o;
    }
    if (lane == 63) wsum[wv] = inc;
    __syncthreads();
    int woff = 0;
    if (wv > 0) woff += wsum[0];
    if (wv > 1) woff += wsum[1];
    if (wv > 2) woff += wsum[2];
    int excl = woff + inc - s;
    if (excl < KNN && excl + s >= KNN) {
        int c = excl;
        int hh[4] = {h0, h1, h2, h3};
        int T = 4 * t;
        #pragma unroll
        for (int j = 0; j < 4; ++j) {
            if (c < KNN && c + hh[j] >= KNN) T = 4 * t + j;
            c += hh[j];
        }
        binT = T;
    }
    __syncthreads();

    int T = binT;
    #pragma unroll
    for (int i = 0; i < 16; ++i) {
        if (rkey(d[i]) <= T) {
            int pos = atomicAdd(&cntC, 1);
            if (pos < 64) { lv[pos] = d[i]; li[pos] = t + 256 * i; }
        }
    }
    __syncthreads();

    if (t < 64) {
        int nc = cntC; nc = nc > 64 ? 64 : nc;
        float v = (t < nc) ? lv[t] : KINF;
        int   m = (t < nc) ? li[t] : 0x7fffffff;
        #pragma unroll
        for (int k = 2; k <= 64; k <<= 1) {
            #pragma unroll
            for (int j = 32; j > 0; j >>= 1) {
                if (j < k) {
                    float ov = __shfl_xor(v, j, 64);
                    int   om = __shfl_xor(m, j, 64);
                    bool keepMin = ((lane & k) == 0) == ((lane & j) == 0);
                    bool less = (ov < v) || (ov == v && om < m);
                    if (keepMin == less) { v = ov; m = om; }
                }
            }
        }
        if (t < KNN) idx_out[(size_t)bn * KNN + t] = m;
    }
}

// ---------------------------------------------------------------------------
// LayerNorm f32 in -> bf16 out
// ---------------------------------------------------------------------------
__global__ __launch_bounds__(256) void ln_kernel(const float* __restrict__ in,
                                                 const float* __restrict__ g,
                                                 const float* __restrict__ bb,
                                                 ushort* __restrict__ out) {
    int r = blockIdx.x;
    int t = threadIdx.x;
    float v = in[(size_t)r * DIM + t];

    __shared__ float sw[4];
    __shared__ float sw2[4];

    float s = v;
    #pragma unroll
    for (int off = 32; off > 0; off >>= 1) s += __shfl_down(s, off);
    if ((t & 63) == 0) sw[t >> 6] = s;
    __syncthreads();
    float mean = (sw[0] + sw[1] + sw[2] + sw[3]) * (1.0f / DIM);

    float dlt = v - mean;
    float s2 = dlt * dlt;
    #pragma unroll
    for (int off = 32; off > 0; off >>= 1) s2 += __shfl_down(s2, off);
    if ((t & 63) == 0) sw2[t >> 6] = s2;
    __syncthreads();
    float var = (sw2[0] + sw2[1] + sw2[2] + sw2[3]) * (1.0f / DIM);

    out[(size_t)r * DIM + t] = f2b(dlt * rsqrtf(var + LN_EPS) * g[t] + bb[t]);
}

// ---------------------------------------------------------------------------
// Transpose-convert: f32 in[R][C] -> bf16 out[C][R]
// ---------------------------------------------------------------------------
__global__ __launch_bounds__(256) void tconv(const float* __restrict__ in,
                                             ushort* __restrict__ out, int R, int C) {
    __shared__ float tile[32][33];
    int tx = threadIdx.x & 31, ty = threadIdx.x >> 5;
    int r0 = blockIdx.y * 32, c0 = blockIdx.x * 32;
    #pragma unroll
    for (int k = 0; k < 4; ++k)
        tile[ty + 8 * k][tx] = in[(size_t)(r0 + ty + 8 * k) * C + c0 + tx];
    __syncthreads();
    #pragma unroll
    for (int k = 0; k < 4; ++k)
        out[(size_t)(c0 + ty + 8 * k) * R + r0 + tx] = f2b(tile[tx][ty + 8 * k]);
}

// straight f32 -> bf16
__global__ __launch_bounds__(256) void conv_k(const float* __restrict__ in,
                                              ushort* __restrict__ out) {
    int i = blockIdx.x * 256 + threadIdx.x;
    out[i] = f2b(in[i]);
}

// w2bd[n][k] = (head(k)==head(n)) ? W_rel2[n&63][k] : 0   (bf16, [256][256])
__global__ __launch_bounds__(256) void w2bd_kernel(const float* __restrict__ W2,
                                                   ushort* __restrict__ out) {
    int n = blockIdx.x, k = threadIdx.x;
    float v = ((k >> 6) == (n >> 6)) ? W2[(n & 63) * 256 + k] : 0.0f;
    out[n * 256 + k] = f2b(v);
}

// bqw[n] = sum_{d in head(n)} bq[d] * W_rel2[n&63][d]   (one block)
__global__ __launch_bounds__(256) void bqw_kernel(const float* __restrict__ bq,
                                                  const float* __restrict__ W2,
                                                  float* __restrict__ out) {
    int n = threadIdx.x;
    int h = n >> 6, i = n & 63;
    float s = 0.f;
    #pragma unroll 8
    for (int dp = 0; dp < 64; ++dp) s += bq[h * 64 + dp] * W2[i * 256 + h * 64 + dp];
    out[n] = s;
}

// bocat[col] = bo[col] + sum_d b_rel2[d] * Wo[d][col]   (one block)
__global__ __launch_bounds__(256) void bocat_kernel(const float* __restrict__ bo,
                                                    const float* __restrict__ br2,
                                                    const float* __restrict__ Wo,
                                                    float* __restrict__ out) {
    int col = threadIdx.x;
    float s = bo[col];
    #pragma unroll 8
    for (int d = 0; d < 256; ++d) s += br2[d] * Wo[d * 256 + col];
    out[col] = s;
}

// BtCat[col][0:256] = WoT[col][:]
__global__ __launch_bounds__(256) void catL_kernel(const ushort* __restrict__ WoT,
                                                   ushort* __restrict__ BtCat) {
    int i = blockIdx.x * 256 + threadIdx.x;   // 65536
    BtCat[(size_t)(i >> 8) * 512 + (i & 255)] = WoT[i];
}

// ---------------------------------------------------------------------------
// MFMA bf16 GEMM: C[M][ldc] = act(A[M][K] @ Bt[N][K]^T + bias) (+res)
// ---------------------------------------------------------------------------
template <int ACT, int OUTBF, int RES>
__global__ __launch_bounds__(256) void gemm_bt(
    const ushort* __restrict__ A, const ushort* __restrict__ Bt,
    const float* __restrict__ bias, const float* __restrict__ res,
    void* __restrict__ Cv, int M, int N, int K, int ldc)
{
    __shared__ ushort As[4096];   // [128][32] bf16, swizzled
    __shared__ ushort Bs[4096];
    const int t = threadIdx.x;
    const int wave = t >> 6, lane = t & 63;
    const int m0 = blockIdx.y * 128, n0 = blockIdx.x * 128;
    const int wr = (wave >> 1) * 64, wc = (wave & 1) * 64;

    f32x4 acc[4][4];
    #pragma unroll
    for (int i = 0; i < 4; ++i)
        #pragma unroll
        for (int j = 0; j < 4; ++j) acc[i][j] = {0.f, 0.f, 0.f, 0.f};

    const int rA0 = (wave * 2 + 0) * 16 + (lane >> 2);
    const int rA1 = (wave * 2 + 1) * 16 + (lane >> 2);
    const int u4 = lane & 3;
    const int sw0 = (rA0 + (rA0 >> 2)) & 3;
    const int sw1 = (rA1 + (rA1 >> 2)) & 3;
    char* ldsA0 = (char*)As + (wave * 2 + 0) * 1024 + lane * 16;
    char* ldsA1 = (char*)As + (wave * 2 + 1) * 1024 + lane * 16;
    char* ldsB0 = (char*)Bs + (wave * 2 + 0) * 1024 + lane * 16;
    char* ldsB1 = (char*)Bs + (wave * 2 + 1) * 1024 + lane * 16;
    const size_t aOff0 = (size_t)(m0 + rA0) * K + (size_t)((u4 ^ sw0) * 8);
    const size_t aOff1 = (size_t)(m0 + rA1) * K + (size_t)((u4 ^ sw1) * 8);
    const size_t bOff0 = (size_t)(n0 + rA0) * K + (size_t)((u4 ^ sw0) * 8);
    const size_t bOff1 = (size_t)(n0 + rA1) * K + (size_t)((u4 ^ sw1) * 8);

    const int cl = lane & 15, gq = lane >> 4;

    for (int k0 = 0; k0 < K; k0 += 32) {
        gload16(A + aOff0 + k0, ldsA0);
        gload16(A + aOff1 + k0, ldsA1);
        gload16(Bt + bOff0 + k0, ldsB0);
        gload16(Bt + bOff1 + k0, ldsB1);
        __syncthreads();

        short8 av[4], bv[4];
        #pragma unroll
        for (int mi = 0; mi < 4; ++mi) {
            int row = wr + mi * 16 + cl;
            int s = (row + (row >> 2)) & 3;
            av[mi] = *(const short8*)((const char*)As + row * 64 + ((gq ^ s) << 4));
            int rowb = wc + mi * 16 + cl;
            int sb = (rowb + (rowb >> 2)) & 3;
            bv[mi] = *(const short8*)((const char*)Bs + rowb * 64 + ((gq ^ sb) << 4));
        }
        #pragma unroll
        for (int mi = 0; mi < 4; ++mi)
            #pragma unroll
            for (int ni = 0; ni < 4; ++ni)
                acc[mi][ni] = __builtin_amdgcn_mfma_f32_16x16x32_bf16(av[mi], bv[ni], acc[mi][ni], 0, 0, 0);
        __syncthreads();
    }

    float* Cf = (float*)Cv;
    ushort* Cb = (ushort*)Cv;
    #pragma unroll
    for (int ni = 0; ni < 4; ++ni) {
        int col = n0 + wc + ni * 16 + cl;
        float bvv = bias ? bias[col] : 0.0f;
        #pragma unroll
        for (int mi = 0; mi < 4; ++mi) {
            #pragma unroll
            for (int r = 0; r < 4; ++r) {
                int row = m0 + wr + mi * 16 + gq * 4 + r;
                float v = acc[mi][ni][r] + bvv;
                if (ACT == 1) v = gelu_f(v);
                if (RES) v += res[(size_t)row * N + col];
                if (OUTBF) Cb[(size_t)row * ldc + col] = f2b(v);
                else       Cf[(size_t)row * ldc + col] = v;
            }
        }
    }
}

// ---------------------------------------------------------------------------
// hid = gelu(rel @ W_rel1 + b_rel1) -> bf16
// ---------------------------------------------------------------------------
__global__ __launch_bounds__(256) void hid_kernel(const float* __restrict__ xyz,
                                                  const int* __restrict__ idx,
                                                  const float* __restrict__ W1,
                                                  const float* __restrict__ b1,
                                                  ushort* __restrict__ hid) {
    int t = threadIdx.x;
    int rl = t >> 6, i = t & 63;
    int row = blockIdx.x * 4 + rl;
    int bn = row >> 4;
    int b = bn >> 12;
    int n = bn & (NPTS - 1);
    int m = idx[row];
    const float* xb = xyz + (size_t)b * NPTS * 3;
    float dx = xb[m * 3 + 0] - xb[n * 3 + 0];
    float dy = xb[m * 3 + 1] - xb[n * 3 + 1];
    float dz = xb[m * 3 + 2] - xb[n * 3 + 2];
    float nr = sqrtf(dx * dx + dy * dy + dz * dz);
    float a = b1[i] + dx * W1[i] + dy * W1[64 + i] + dz * W1[128 + i] + nr * W1[192 + i];
    hid[(size_t)row * 64 + i] = f2b(gelu_f(a));
}

// ---------------------------------------------------------------------------
// Attention v2 (factored, W2 contractions hoisted to GEMMs):
//   logit_hj = ( q_h . k_j|h  +  qw_h . hid_j ) / 8
//   outputs: ab[bn][0:256]   = partial_d = sum_j p_j v_j[d]
//            ab[bn][256:512] = hp[(h,i)] = sum_j p_hj hid_j[i]
//   (ab right half holds qwg on entry; overwritten after staging)
// 8 points/block; wave == head; XCD-contiguous block swizzle.
// ---------------------------------------------------------------------------
#define PTS 8
__global__ __launch_bounds__(256) void attn_kernel(
    const int* __restrict__ idx,
    const ushort* __restrict__ qb, const ushort* __restrict__ kb,
    const ushort* __restrict__ vb, const ushort* __restrict__ hidg,
    ushort* __restrict__ ab)
{
    __shared__ float qS[256];
    __shared__ float qwS[256];
    __shared__ float psS[64];
    __shared__ uint4 hidS4[16 * 9];   // [16 rows][stride 144B], 8 valid chunks
    __shared__ int   nbAll[128];
    ushort* hidS = (ushort*)hidS4;

    const int t = threadIdx.x;
    const int h = t >> 6, lane = t & 63;
    const int bid = blockIdx.x;
    const int blk = ((bid & 7) << 8) | (bid >> 3);   // 2048 = 8*256, bijective
    const int bn0 = blk * PTS;
    const int R0 = blk * (PTS * 16);

    if (t < 128) nbAll[t] = idx[R0 + t];

    for (int pt = 0; pt < PTS; ++pt) {
        const int bn = bn0 + pt;
        const size_t base = (size_t)(bn >> 12) * NPTS;

        qS[t]  = b2f(qb[(size_t)bn * 256 + t]);
        qwS[t] = b2f(ab[(size_t)bn * 512 + 256 + t]);
        if (t < 128) {
            int j = t >> 3, c = t & 7;
            hidS4[j * 9 + c] = *(const uint4*)(hidg + (size_t)(R0 + pt * 16 + j) * 64 + c * 8);
        }
        __syncthreads();

        // logits + softmax (wave h = head h; lane = j*4+sub)
        {
            int j = lane >> 2, sub = lane & 3;
            int m = nbAll[pt * 16 + j];
            const ushort* krow = kb + (base + m) * 256 + h * 64 + sub * 16;
            uint4 ka = *(const uint4*)krow;
            uint4 kc = *(const uint4*)(krow + 8);
            const float* qp = &qS[h * 64 + sub * 16];
            float d1 = dot8(ka, qp) + dot8(kc, qp + 8);
            const ushort* hrow = hidS + j * 72 + sub * 16;
            uint4 ha = *(const uint4*)hrow;
            uint4 hc = *(const uint4*)(hrow + 8);
            const float* qwp = &qwS[h * 64 + sub * 16];
            float d2 = dot8(ha, qwp) + dot8(hc, qwp + 8);
            float pp = d1 + d2;
            pp += __shfl_xor(pp, 1, 64);
            pp += __shfl_xor(pp, 2, 64);
            pp *= 0.125f;
            float mx = pp;
            mx = fmaxf(mx, __shfl_xor(mx, 4, 64));
            mx = fmaxf(mx, __shfl_xor(mx, 8, 64));
            mx = fmaxf(mx, __shfl_xor(mx, 16, 64));
            mx = fmaxf(mx, __shfl_xor(mx, 32, 64));
            float e = expf(pp - mx);
            float ss = e;
            ss += __shfl_xor(ss, 4, 64);
            ss += __shfl_xor(ss, 8, 64);
            ss += __shfl_xor(ss, 16, 64);
            ss += __shfl_xor(ss, 32, 64);
            float pj = e / ss;
            if (sub == 0) psS[h * 16 + j] = pj;
        }
        __syncthreads();

        // partial + hp
        {
            float o = 0.f, hpv = 0.f;
            #pragma unroll
            for (int j = 0; j < 16; ++j) {
                float p = psS[h * 16 + j];
                int m = nbAll[pt * 16 + j];
                o   += p * b2f(vb[(base + m) * 256 + t]);
                hpv += p * b2f(hidS[j * 72 + lane]);
            }
            ab[(size_t)bn * 512 + t]       = f2b(o);
            ab[(size_t)bn * 512 + 256 + t] = f2b(hpv);
        }
        __syncthreads();
    }
}

// ---------------------------------------------------------------------------
extern "C" void kernel_launch(void* const* d_in, const int* in_sizes, int n_in,
                              void* d_out, int out_size, void* d_ws, size_t ws_size,
                              hipStream_t stream) {
    const float* xyz    = (const float*)d_in[0];
    const float* feats  = (const float*)d_in[1];
    const float* ln_q_g = (const float*)d_in[2];
    const float* ln_q_b = (const float*)d_in[3];
    const float* Wq     = (const float*)d_in[4];
    const float* bq     = (const float*)d_in[5];
    const float* Wk     = (const float*)d_in[6];
    const float* bk     = (const float*)d_in[7];
    const float* Wv     = (const float*)d_in[8];
    const float* bv     = (const float*)d_in[9];
    const float* W_rel1 = (const float*)d_in[10];
    const float* b_rel1 = (const float*)d_in[11];
    const float* W_rel2 = (const float*)d_in[12];
    const float* b_rel2 = (const float*)d_in[13];
    const float* Wo     = (const float*)d_in[14];
    const float* bo     = (const float*)d_in[15];
    const float* ln_f_g = (const float*)d_in[16];
    const float* ln_f_b = (const float*)d_in[17];
    const float* W_ff1  = (const float*)d_in[18];
    const float* b_ff1  = (const float*)d_in[19];
    const float* W_ff2  = (const float*)d_in[20];
    const float* b_ff2  = (const float*)d_in[21];
    (void)in_sizes; (void)n_in; (void)out_size; (void)ws_size;

    char* ws = (char*)d_ws;
    const size_t MB = 1u << 20;
    int*    idx    = (int*)ws;                       // 1 MB
    ushort* xb     = (ushort*)(ws + 1 * MB);         // 8 MB  (LN out)
    ushort* qb     = (ushort*)(ws + 9 * MB);         // 8 MB  (q; reused as h)
    ushort* kb     = (ushort*)(ws + 17 * MB);        // 8 MB
    ushort* vb     = (ushort*)(ws + 25 * MB);        // 8 MB
    ushort* hidg   = (ushort*)(ws + 33 * MB);        // 32 MB (hid; reused as ff1 out)
    float*  feats1 = (float*)(ws + 65 * MB);         // 16 MB
    ushort* ab     = (ushort*)(ws + 81 * MB);        // 16 MB [16384][512]; right half = qwg
    ushort* WqT    = (ushort*)(ws + 97 * MB);        // weights below
    ushort* WkT    = WqT + 65536;
    ushort* WvT    = WkT + 65536;
    ushort* WoT    = WvT + 65536;
    ushort* Wf1T   = WoT + 65536;                    // [1024][256]
    ushort* Wf2T   = Wf1T + 262144;                  // [256][1024]
    ushort* Wq_bf  = Wf2T + 262144;                  // [256][256] row-major
    ushort* w2bd   = Wq_bf + 65536;                  // [256][256]
    ushort* WqwT   = w2bd + 65536;                   // [256][256]
    ushort* BtCat  = WqwT + 65536;                   // [256][512]
    float*  bqw    = (float*)(BtCat + 131072);       // 256
    float*  boc    = bqw + 256;                      // 256
    ushort* hb   = qb;
    ushort* ff1b = hidg;

    // ---- weight preprocessing ----
    tconv<<<dim3(8, 8),  256, 0, stream>>>(Wq, WqT, 256, 256);
    tconv<<<dim3(8, 8),  256, 0, stream>>>(Wk, WkT, 256, 256);
    tconv<<<dim3(8, 8),  256, 0, stream>>>(Wv, WvT, 256, 256);
    tconv<<<dim3(8, 8),  256, 0, stream>>>(Wo, WoT, 256, 256);
    tconv<<<dim3(32, 8), 256, 0, stream>>>(W_ff1, Wf1T, 256, 1024);
    tconv<<<dim3(8, 32), 256, 0, stream>>>(W_ff2, Wf2T, 1024, 256);
    conv_k<<<256, 256, 0, stream>>>(Wq, Wq_bf);
    w2bd_kernel<<<256, 256, 0, stream>>>(W_rel2, w2bd);
    // WqwT[n][e] = sum_d w2bd[n][d] * Wq[e][d]
    gemm_bt<0, 1, 0><<<dim3(2, 2), 256, 0, stream>>>(w2bd, Wq_bf, nullptr, nullptr, WqwT, 256, 256, 256, 256);
    // BtCat right: W2Wo[col][n] = sum_d WoT[col][d] * w2bd[n][d]
    gemm_bt<0, 1, 0><<<dim3(2, 2), 256, 0, stream>>>(WoT, w2bd, nullptr, nullptr, BtCat + 256, 256, 256, 256, 512);
    catL_kernel<<<256, 256, 0, stream>>>(WoT, BtCat);
    bqw_kernel<<<1, 256, 0, stream>>>(bq, W_rel2, bqw);
    bocat_kernel<<<1, 256, 0, stream>>>(bo, b_rel2, Wo, boc);

    // ---- main pipeline ----
    knn_kernel<<<MTOT, 256, 0, stream>>>(xyz, idx);
    ln_kernel<<<MTOT, 256, 0, stream>>>(feats, ln_q_g, ln_q_b, xb);

    gemm_bt<0, 1, 0><<<dim3(2, 128), 256, 0, stream>>>(xb, WqT, bq, nullptr, qb, MTOT, 256, 256, 256);
    gemm_bt<0, 1, 0><<<dim3(2, 128), 256, 0, stream>>>(xb, WkT, bk, nullptr, kb, MTOT, 256, 256, 256);
    gemm_bt<0, 1, 0><<<dim3(2, 128), 256, 0, stream>>>(xb, WvT, bv, nullptr, vb, MTOT, 256, 256, 256);
    // qwg -> ab right half
    gemm_bt<0, 1, 0><<<dim3(2, 128), 256, 0, stream>>>(xb, WqwT, bqw, nullptr, ab + 256, MTOT, 256, 256, 512);

    hid_kernel<<<MTOT * 16 / 4, 256, 0, stream>>>(xyz, idx, W_rel1, b_rel1, hidg);
    attn_kernel<<<MTOT / PTS, 256, 0, stream>>>(idx, qb, kb, vb, hidg, ab);

    // feats1 = [partial|hp] @ BtCat^T + boc + feats
    gemm_bt<0, 0, 1><<<dim3(2, 128), 256, 0, stream>>>(ab, BtCat, boc, feats, feats1, MTOT, 256, 512, 256);
    ln_kernel<<<MTOT, 256, 0, stream>>>(feats1, ln_f_g, ln_f_b, hb);
    gemm_bt<1, 1, 0><<<dim3(8, 128), 256, 0, stream>>>(hb, Wf1T, b_ff1, nullptr, ff1b, MTOT, 1024, 256, 1024);
    gemm_bt<0, 0, 1><<<dim3(2, 128), 256, 0, stream>>>(ff1b, Wf2T, b_ff2, feats1, (float*)d_out, MTOT, 256, 1024, 256);
}

// Round 7
// 348.694 us; speedup vs baseline: 5.3227x; 1.0609x over previous
//
#include <hip/hip_runtime.h>
#include <hip/hip_bf16.h>
#include <math.h>

#define NB 4
#define NPTS 4096
#define DIM 256
#define KNN 16
#define HID 64
#define FFDIM 1024
#define LN_EPS 1e-5f
#define MTOT (NB * NPTS)
#define KINF 3e38f

typedef __attribute__((ext_vector_type(8))) short short8;
typedef __attribute__((ext_vector_type(4))) float f32x4;

__device__ __forceinline__ float gelu_f(float x) {
    return 0.5f * x * (1.0f + erff(x * 0.7071067811865476f));
}
__device__ __forceinline__ float b2f(ushort u) {
    return __uint_as_float(((unsigned)u) << 16);
}
__device__ __forceinline__ ushort f2b(float f) {
    unsigned u = __float_as_uint(f);
    return (ushort)((u + 0x7fffu + ((u >> 16) & 1u)) >> 16);
}
__device__ __forceinline__ void gload16(const void* g, void* l) {
    __builtin_amdgcn_global_load_lds((const __attribute__((address_space(1))) void*)g,
                                     (__attribute__((address_space(3))) void*)l, 16, 0, 0);
}
// dot of 8 bf16 (packed in uint4) with 8 consecutive f32
__device__ __forceinline__ float dot8(uint4 w, const float* q) {
    float s = 0.f;
    s += b2f((ushort)(w.x & 0xffff)) * q[0]; s += b2f((ushort)(w.x >> 16)) * q[1];
    s += b2f((ushort)(w.y & 0xffff)) * q[2]; s += b2f((ushort)(w.y >> 16)) * q[3];
    s += b2f((ushort)(w.z & 0xffff)) * q[4]; s += b2f((ushort)(w.z >> 16)) * q[5];
    s += b2f((ushort)(w.w & 0xffff)) * q[6]; s += b2f((ushort)(w.w >> 16)) * q[7];
    return s;
}

// ---------------------------------------------------------------------------
// KNN v4: one block per query; distances in registers. Threshold = 16th
// smallest of the 256 per-thread minima (guarantees >=16 candidates <= T):
// per-wave value bitonic sort-64 -> 4x16 to LDS -> wave0 sort-64 -> T.
// Compact d<=T (~20 cands, cap 64), wave0 lexicographic (d,idx) sort, write 16.
// No histogram, no hot-address atomics.
// ---------------------------------------------------------------------------
__global__ __launch_bounds__(256) void knn_kernel(const float* __restrict__ xyz,
                                                  int* __restrict__ idx_out) {
    int bn = blockIdx.x;
    int b = bn >> 12;
    int n = bn & (NPTS - 1);
    const float* base = xyz + (size_t)b * NPTS * 3;
    int t = threadIdx.x;
    int lane = t & 63, wv = t >> 6;

    __shared__ float wval[64];
    __shared__ float Tsh;
    __shared__ int   cntC;
    __shared__ float lv[64];
    __shared__ int   li[64];

    if (t == 0) cntC = 0;

    float qx = base[n * 3 + 0], qy = base[n * 3 + 1], qz = base[n * 3 + 2];
    float sqn = qx * qx + qy * qy + qz * qz;

    float d[16];
    #pragma unroll
    for (int i = 0; i < 16; ++i) {
        int m = t + 256 * i;
        float x = base[m * 3 + 0], y = base[m * 3 + 1], z = base[m * 3 + 2];
        float sqm = x * x + y * y + z * z;
        float dot = qx * x + qy * y + qz * z;
        float dd = sqn + sqm - 2.0f * dot;
        d[i] = (m == n) ? KINF : dd;
    }

    float lmin = d[0];
    #pragma unroll
    for (int i = 1; i < 16; ++i) lmin = fminf(lmin, d[i]);

    // per-wave bitonic sort (ascending) of 64 lane-mins; lanes 0..15 hold wave top-16
    {
        float v = lmin;
        #pragma unroll
        for (int k = 2; k <= 64; k <<= 1) {
            #pragma unroll
            for (int j = 32; j > 0; j >>= 1) {
                if (j < k) {
                    float ov = __shfl_xor(v, j, 64);
                    bool keepMin = ((lane & k) == 0) == ((lane & j) == 0);
                    if (keepMin == (ov < v)) v = ov;
                }
            }
        }
        if (lane < 16) wval[wv * 16 + lane] = v;
    }
    __syncthreads();

    // wave 0: sort the 64 collected values; lane 15 = block 16th-smallest lane-min
    if (wv == 0) {
        float v = wval[lane];
        #pragma unroll
        for (int k = 2; k <= 64; k <<= 1) {
            #pragma unroll
            for (int j = 32; j > 0; j >>= 1) {
                if (j < k) {
                    float ov = __shfl_xor(v, j, 64);
                    bool keepMin = ((lane & k) == 0) == ((lane & j) == 0);
                    if (keepMin == (ov < v)) v = ov;
                }
            }
        }
        if (lane == 15) Tsh = v;
    }
    __syncthreads();

    float T = Tsh;
    #pragma unroll
    for (int i = 0; i < 16; ++i) {
        if (d[i] <= T) {
            int pos = atomicAdd(&cntC, 1);
            if (pos < 64) { lv[pos] = d[i]; li[pos] = t + 256 * i; }
        }
    }
    __syncthreads();

    if (wv == 0) {
        int nc = cntC; nc = nc > 64 ? 64 : nc;
        float v = (lane < nc) ? lv[lane] : KINF;
        int   m = (lane < nc) ? li[lane] : 0x7fffffff;
        #pragma unroll
        for (int k = 2; k <= 64; k <<= 1) {
            #pragma unroll
            for (int j = 32; j > 0; j >>= 1) {
                if (j < k) {
                    float ov = __shfl_xor(v, j, 64);
                    int   om = __shfl_xor(m, j, 64);
                    bool keepMin = ((lane & k) == 0) == ((lane & j) == 0);
                    bool less = (ov < v) || (ov == v && om < m);
                    if (keepMin == less) { v = ov; m = om; }
                }
            }
        }
        if (lane < KNN) idx_out[(size_t)bn * KNN + lane] = m;
    }
}

// ---------------------------------------------------------------------------
// LayerNorm f32 in -> bf16 out
// ---------------------------------------------------------------------------
__global__ __launch_bounds__(256) void ln_kernel(const float* __restrict__ in,
                                                 const float* __restrict__ g,
                                                 const float* __restrict__ bb,
                                                 ushort* __restrict__ out) {
    int r = blockIdx.x;
    int t = threadIdx.x;
    float v = in[(size_t)r * DIM + t];

    __shared__ float sw[4];
    __shared__ float sw2[4];

    float s = v;
    #pragma unroll
    for (int off = 32; off > 0; off >>= 1) s += __shfl_down(s, off);
    if ((t & 63) == 0) sw[t >> 6] = s;
    __syncthreads();
    float mean = (sw[0] + sw[1] + sw[2] + sw[3]) * (1.0f / DIM);

    float dlt = v - mean;
    float s2 = dlt * dlt;
    #pragma unroll
    for (int off = 32; off > 0; off >>= 1) s2 += __shfl_down(s2, off);
    if ((t & 63) == 0) sw2[t >> 6] = s2;
    __syncthreads();
    float var = (sw2[0] + sw2[1] + sw2[2] + sw2[3]) * (1.0f / DIM);

    out[(size_t)r * DIM + t] = f2b(dlt * rsqrtf(var + LN_EPS) * g[t] + bb[t]);
}

// ---------------------------------------------------------------------------
// Transpose-convert: f32 in[R][C] -> bf16 out[C][R]
// ---------------------------------------------------------------------------
__global__ __launch_bounds__(256) void tconv(const float* __restrict__ in,
                                             ushort* __restrict__ out, int R, int C) {
    __shared__ float tile[32][33];
    int tx = threadIdx.x & 31, ty = threadIdx.x >> 5;
    int r0 = blockIdx.y * 32, c0 = blockIdx.x * 32;
    #pragma unroll
    for (int k = 0; k < 4; ++k)
        tile[ty + 8 * k][tx] = in[(size_t)(r0 + ty + 8 * k) * C + c0 + tx];
    __syncthreads();
    #pragma unroll
    for (int k = 0; k < 4; ++k)
        out[(size_t)(c0 + ty + 8 * k) * R + r0 + tx] = f2b(tile[tx][ty + 8 * k]);
}

// straight f32 -> bf16
__global__ __launch_bounds__(256) void conv_k(const float* __restrict__ in,
                                              ushort* __restrict__ out) {
    int i = blockIdx.x * 256 + threadIdx.x;
    out[i] = f2b(in[i]);
}

// w2bd[n][k] = (head(k)==head(n)) ? W_rel2[n&63][k] : 0   (bf16, [256][256])
__global__ __launch_bounds__(256) void w2bd_kernel(const float* __restrict__ W2,
                                                   ushort* __restrict__ out) {
    int n = blockIdx.x, k = threadIdx.x;
    float v = ((k >> 6) == (n >> 6)) ? W2[(n & 63) * 256 + k] : 0.0f;
    out[n * 256 + k] = f2b(v);
}

// bqw[n] = sum_{d in head(n)} bq[d] * W_rel2[n&63][d]   (one block)
__global__ __launch_bounds__(256) void bqw_kernel(const float* __restrict__ bq,
                                                  const float* __restrict__ W2,
                                                  float* __restrict__ out) {
    int n = threadIdx.x;
    int h = n >> 6, i = n & 63;
    float s = 0.f;
    #pragma unroll 8
    for (int dp = 0; dp < 64; ++dp) s += bq[h * 64 + dp] * W2[i * 256 + h * 64 + dp];
    out[n] = s;
}

// bocat[col] = bo[col] + sum_d b_rel2[d] * Wo[d][col]   (one block)
__global__ __launch_bounds__(256) void bocat_kernel(const float* __restrict__ bo,
                                                    const float* __restrict__ br2,
                                                    const float* __restrict__ Wo,
                                                    float* __restrict__ out) {
    int col = threadIdx.x;
    float s = bo[col];
    #pragma unroll 8
    for (int d = 0; d < 256; ++d) s += br2[d] * Wo[d * 256 + col];
    out[col] = s;
}

// BtCat[col][0:256] = WoT[col][:]
__global__ __launch_bounds__(256) void catL_kernel(const ushort* __restrict__ WoT,
                                                   ushort* __restrict__ BtCat) {
    int i = blockIdx.x * 256 + threadIdx.x;   // 65536
    BtCat[(size_t)(i >> 8) * 512 + (i & 255)] = WoT[i];
}

// ---------------------------------------------------------------------------
// MFMA bf16 GEMM: C[M][ldc] = act(A[M][K] @ Bt[N][K]^T + bias) (+res)
// ---------------------------------------------------------------------------
template <int ACT, int OUTBF, int RES>
__global__ __launch_bounds__(256) void gemm_bt(
    const ushort* __restrict__ A, const ushort* __restrict__ Bt,
    const float* __restrict__ bias, const float* __restrict__ res,
    void* __restrict__ Cv, int M, int N, int K, int ldc)
{
    __shared__ ushort As[4096];   // [128][32] bf16, swizzled
    __shared__ ushort Bs[4096];
    const int t = threadIdx.x;
    const int wave = t >> 6, lane = t & 63;
    const int m0 = blockIdx.y * 128, n0 = blockIdx.x * 128;
    const int wr = (wave >> 1) * 64, wc = (wave & 1) * 64;

    f32x4 acc[4][4];
    #pragma unroll
    for (int i = 0; i < 4; ++i)
        #pragma unroll
        for (int j = 0; j < 4; ++j) acc[i][j] = {0.f, 0.f, 0.f, 0.f};

    const int rA0 = (wave * 2 + 0) * 16 + (lane >> 2);
    const int rA1 = (wave * 2 + 1) * 16 + (lane >> 2);
    const int u4 = lane & 3;
    const int sw0 = (rA0 + (rA0 >> 2)) & 3;
    const int sw1 = (rA1 + (rA1 >> 2)) & 3;
    char* ldsA0 = (char*)As + (wave * 2 + 0) * 1024 + lane * 16;
    char* ldsA1 = (char*)As + (wave * 2 + 1) * 1024 + lane * 16;
    char* ldsB0 = (char*)Bs + (wave * 2 + 0) * 1024 + lane * 16;
    char* ldsB1 = (char*)Bs + (wave * 2 + 1) * 1024 + lane * 16;
    const size_t aOff0 = (size_t)(m0 + rA0) * K + (size_t)((u4 ^ sw0) * 8);
    const size_t aOff1 = (size_t)(m0 + rA1) * K + (size_t)((u4 ^ sw1) * 8);
    const size_t bOff0 = (size_t)(n0 + rA0) * K + (size_t)((u4 ^ sw0) * 8);
    const size_t bOff1 = (size_t)(n0 + rA1) * K + (size_t)((u4 ^ sw1) * 8);

    const int cl = lane & 15, gq = lane >> 4;

    for (int k0 = 0; k0 < K; k0 += 32) {
        gload16(A + aOff0 + k0, ldsA0);
        gload16(A + aOff1 + k0, ldsA1);
        gload16(Bt + bOff0 + k0, ldsB0);
        gload16(Bt + bOff1 + k0, ldsB1);
        __syncthreads();

        short8 av[4], bv[4];
        #pragma unroll
        for (int mi = 0; mi < 4; ++mi) {
            int row = wr + mi * 16 + cl;
            int s = (row + (row >> 2)) & 3;
            av[mi] = *(const short8*)((const char*)As + row * 64 + ((gq ^ s) << 4));
            int rowb = wc + mi * 16 + cl;
            int sb = (rowb + (rowb >> 2)) & 3;
            bv[mi] = *(const short8*)((const char*)Bs + rowb * 64 + ((gq ^ sb) << 4));
        }
        #pragma unroll
        for (int mi = 0; mi < 4; ++mi)
            #pragma unroll
            for (int ni = 0; ni < 4; ++ni)
                acc[mi][ni] = __builtin_amdgcn_mfma_f32_16x16x32_bf16(av[mi], bv[ni], acc[mi][ni], 0, 0, 0);
        __syncthreads();
    }

    float* Cf = (float*)Cv;
    ushort* Cb = (ushort*)Cv;
    #pragma unroll
    for (int ni = 0; ni < 4; ++ni) {
        int col = n0 + wc + ni * 16 + cl;
        float bvv = bias ? bias[col] : 0.0f;
        #pragma unroll
        for (int mi = 0; mi < 4; ++mi) {
            #pragma unroll
            for (int r = 0; r < 4; ++r) {
                int row = m0 + wr + mi * 16 + gq * 4 + r;
                float v = acc[mi][ni][r] + bvv;
                if (ACT == 1) v = gelu_f(v);
                if (RES) v += res[(size_t)row * N + col];
                if (OUTBF) Cb[(size_t)row * ldc + col] = f2b(v);
                else       Cf[(size_t)row * ldc + col] = v;
            }
        }
    }
}

// ---------------------------------------------------------------------------
// hid = gelu(rel @ W_rel1 + b_rel1) -> bf16
// ---------------------------------------------------------------------------
__global__ __launch_bounds__(256) void hid_kernel(const float* __restrict__ xyz,
                                                  const int* __restrict__ idx,
                                                  const float* __restrict__ W1,
                                                  const float* __restrict__ b1,
                                                  ushort* __restrict__ hid) {
    int t = threadIdx.x;
    int rl = t >> 6, i = t & 63;
    int row = blockIdx.x * 4 + rl;
    int bn = row >> 4;
    int b = bn >> 12;
    int n = bn & (NPTS - 1);
    int m = idx[row];
    const float* xb = xyz + (size_t)b * NPTS * 3;
    float dx = xb[m * 3 + 0] - xb[n * 3 + 0];
    float dy = xb[m * 3 + 1] - xb[n * 3 + 1];
    float dz = xb[m * 3 + 2] - xb[n * 3 + 2];
    float nr = sqrtf(dx * dx + dy * dy + dz * dz);
    float a = b1[i] + dx * W1[i] + dy * W1[64 + i] + dz * W1[128 + i] + nr * W1[192 + i];
    hid[(size_t)row * 64 + i] = f2b(gelu_f(a));
}

// ---------------------------------------------------------------------------
// Attention v2 (factored, W2 contractions hoisted to GEMMs):
//   logit_hj = ( q_h . k_j|h  +  qw_h . hid_j ) / 8
//   outputs: ab[bn][0:256]   = partial_d = sum_j p_j v_j[d]
//            ab[bn][256:512] = hp[(h,i)] = sum_j p_hj hid_j[i]
//   (ab right half holds qwg on entry; overwritten after staging)
// 8 points/block; wave == head; XCD-contiguous block swizzle.
// ---------------------------------------------------------------------------
#define PTS 8
__global__ __launch_bounds__(256) void attn_kernel(
    const int* __restrict__ idx,
    const ushort* __restrict__ qb, const ushort* __restrict__ kb,
    const ushort* __restrict__ vb, const ushort* __restrict__ hidg,
    ushort* __restrict__ ab)
{
    __shared__ float qS[256];
    __shared__ float qwS[256];
    __shared__ float psS[64];
    __shared__ uint4 hidS4[16 * 9];   // [16 rows][stride 144B], 8 valid chunks
    __shared__ int   nbAll[128];
    ushort* hidS = (ushort*)hidS4;

    const int t = threadIdx.x;
    const int h = t >> 6, lane = t & 63;
    const int bid = blockIdx.x;
    const int blk = ((bid & 7) << 8) | (bid >> 3);   // 2048 = 8*256, bijective
    const int bn0 = blk * PTS;
    const int R0 = blk * (PTS * 16);

    if (t < 128) nbAll[t] = idx[R0 + t];

    for (int pt = 0; pt < PTS; ++pt) {
        const int bn = bn0 + pt;
        const size_t base = (size_t)(bn >> 12) * NPTS;

        qS[t]  = b2f(qb[(size_t)bn * 256 + t]);
        qwS[t] = b2f(ab[(size_t)bn * 512 + 256 + t]);
        if (t < 128) {
            int j = t >> 3, c = t & 7;
            hidS4[j * 9 + c] = *(const uint4*)(hidg + (size_t)(R0 + pt * 16 + j) * 64 + c * 8);
        }
        __syncthreads();

        // logits + softmax (wave h = head h; lane = j*4+sub)
        {
            int j = lane >> 2, sub = lane & 3;
            int m = nbAll[pt * 16 + j];
            const ushort* krow = kb + (base + m) * 256 + h * 64 + sub * 16;
            uint4 ka = *(const uint4*)krow;
            uint4 kc = *(const uint4*)(krow + 8);
            const float* qp = &qS[h * 64 + sub * 16];
            float d1 = dot8(ka, qp) + dot8(kc, qp + 8);
            const ushort* hrow = hidS + j * 72 + sub * 16;
            uint4 ha = *(const uint4*)hrow;
            uint4 hc = *(const uint4*)(hrow + 8);
            const float* qwp = &qwS[h * 64 + sub * 16];
            float d2 = dot8(ha, qwp) + dot8(hc, qwp + 8);
            float pp = d1 + d2;
            pp += __shfl_xor(pp, 1, 64);
            pp += __shfl_xor(pp, 2, 64);
            pp *= 0.125f;
            float mx = pp;
            mx = fmaxf(mx, __shfl_xor(mx, 4, 64));
            mx = fmaxf(mx, __shfl_xor(mx, 8, 64));
            mx = fmaxf(mx, __shfl_xor(mx, 16, 64));
            mx = fmaxf(mx, __shfl_xor(mx, 32, 64));
            float e = expf(pp - mx);
            float ss = e;
            ss += __shfl_xor(ss, 4, 64);
            ss += __shfl_xor(ss, 8, 64);
            ss += __shfl_xor(ss, 16, 64);
            ss += __shfl_xor(ss, 32, 64);
            float pj = e / ss;
            if (sub == 0) psS[h * 16 + j] = pj;
        }
        __syncthreads();

        // partial + hp
        {
            float o = 0.f, hpv = 0.f;
            #pragma unroll
            for (int j = 0; j < 16; ++j) {
                float p = psS[h * 16 + j];
                int m = nbAll[pt * 16 + j];
                o   += p * b2f(vb[(base + m) * 256 + t]);
                hpv += p * b2f(hidS[j * 72 + lane]);
            }
            ab[(size_t)bn * 512 + t]       = f2b(o);
            ab[(size_t)bn * 512 + 256 + t] = f2b(hpv);
        }
        __syncthreads();
    }
}

// ---------------------------------------------------------------------------
extern "C" void kernel_launch(void* const* d_in, const int* in_sizes, int n_in,
                              void* d_out, int out_size, void* d_ws, size_t ws_size,
                              hipStream_t stream) {
    const float* xyz    = (const float*)d_in[0];
    const float* feats  = (const float*)d_in[1];
    const float* ln_q_g = (const float*)d_in[2];
    const float* ln_q_b = (const float*)d_in[3];
    const float* Wq     = (const float*)d_in[4];
    const float* bq     = (const float*)d_in[5];
    const float* Wk     = (const float*)d_in[6];
    const float* bk     = (const float*)d_in[7];
    const float* Wv     = (const float*)d_in[8];
    const float* bv     = (const float*)d_in[9];
    const float* W_rel1 = (const float*)d_in[10];
    const float* b_rel1 = (const float*)d_in[11];
    const float* W_rel2 = (const float*)d_in[12];
    const float* b_rel2 = (const float*)d_in[13];
    const float* Wo     = (const float*)d_in[14];
    const float* bo     = (const float*)d_in[15];
    const float* ln_f_g = (const float*)d_in[16];
    const float* ln_f_b = (const float*)d_in[17];
    const float* W_ff1  = (const float*)d_in[18];
    const float* b_ff1  = (const float*)d_in[19];
    const float* W_ff2  = (const float*)d_in[20];
    const float* b_ff2  = (const float*)d_in[21];
    (void)in_sizes; (void)n_in; (void)out_size; (void)ws_size;

    char* ws = (char*)d_ws;
    const size_t MB = 1u << 20;
    int*    idx    = (int*)ws;                       // 1 MB
    ushort* xb     = (ushort*)(ws + 1 * MB);         // 8 MB  (LN out)
    ushort* qb     = (ushort*)(ws + 9 * MB);         // 8 MB  (q; reused as h)
    ushort* kb     = (ushort*)(ws + 17 * MB);        // 8 MB
    ushort* vb     = (ushort*)(ws + 25 * MB);        // 8 MB
    ushort* hidg   = (ushort*)(ws + 33 * MB);        // 32 MB (hid; reused as ff1 out)
    float*  feats1 = (float*)(ws + 65 * MB);         // 16 MB
    ushort* ab     = (ushort*)(ws + 81 * MB);        // 16 MB [16384][512]; right half = qwg
    ushort* WqT    = (ushort*)(ws + 97 * MB);        // weights below
    ushort* WkT    = WqT + 65536;
    ushort* WvT    = WkT + 65536;
    ushort* WoT    = WvT + 65536;
    ushort* Wf1T   = WoT + 65536;                    // [1024][256]
    ushort* Wf2T   = Wf1T + 262144;                  // [256][1024]
    ushort* Wq_bf  = Wf2T + 262144;                  // [256][256] row-major
    ushort* w2bd   = Wq_bf + 65536;                  // [256][256]
    ushort* WqwT   = w2bd + 65536;                   // [256][256]
    ushort* BtCat  = WqwT + 65536;                   // [256][512]
    float*  bqw    = (float*)(BtCat + 131072);       // 256
    float*  boc    = bqw + 256;                      // 256
    ushort* hb   = qb;
    ushort* ff1b = hidg;

    // ---- weight preprocessing ----
    tconv<<<dim3(8, 8),  256, 0, stream>>>(Wq, WqT, 256, 256);
    tconv<<<dim3(8, 8),  256, 0, stream>>>(Wk, WkT, 256, 256);
    tconv<<<dim3(8, 8),  256, 0, stream>>>(Wv, WvT, 256, 256);
    tconv<<<dim3(8, 8),  256, 0, stream>>>(Wo, WoT, 256, 256);
    tconv<<<dim3(32, 8), 256, 0, stream>>>(W_ff1, Wf1T, 256, 1024);
    tconv<<<dim3(8, 32), 256, 0, stream>>>(W_ff2, Wf2T, 1024, 256);
    conv_k<<<256, 256, 0, stream>>>(Wq, Wq_bf);
    w2bd_kernel<<<256, 256, 0, stream>>>(W_rel2, w2bd);
    // WqwT[n][e] = sum_d w2bd[n][d] * Wq[e][d]
    gemm_bt<0, 1, 0><<<dim3(2, 2), 256, 0, stream>>>(w2bd, Wq_bf, nullptr, nullptr, WqwT, 256, 256, 256, 256);
    // BtCat right: W2Wo[col][n] = sum_d WoT[col][d] * w2bd[n][d]
    gemm_bt<0, 1, 0><<<dim3(2, 2), 256, 0, stream>>>(WoT, w2bd, nullptr, nullptr, BtCat + 256, 256, 256, 256, 512);
    catL_kernel<<<256, 256, 0, stream>>>(WoT, BtCat);
    bqw_kernel<<<1, 256, 0, stream>>>(bq, W_rel2, bqw);
    bocat_kernel<<<1, 256, 0, stream>>>(bo, b_rel2, Wo, boc);

    // ---- main pipeline ----
    knn_kernel<<<MTOT, 256, 0, stream>>>(xyz, idx);
    ln_kernel<<<MTOT, 256, 0, stream>>>(feats, ln_q_g, ln_q_b, xb);

    gemm_bt<0, 1, 0><<<dim3(2, 128), 256, 0, stream>>>(xb, WqT, bq, nullptr, qb, MTOT, 256, 256, 256);
    gemm_bt<0, 1, 0><<<dim3(2, 128), 256, 0, stream>>>(xb, WkT, bk, nullptr, kb, MTOT, 256, 256, 256);
    gemm_bt<0, 1, 0><<<dim3(2, 128), 256, 0, stream>>>(xb, WvT, bv, nullptr, vb, MTOT, 256, 256, 256);
    // qwg -> ab right half
    gemm_bt<0, 1, 0><<<dim3(2, 128), 256, 0, stream>>>(xb, WqwT, bqw, nullptr, ab + 256, MTOT, 256, 256, 512);

    hid_kernel<<<MTOT * 16 / 4, 256, 0, stream>>>(xyz, idx, W_rel1, b_rel1, hidg);
    attn_kernel<<<MTOT / PTS, 256, 0, stream>>>(idx, qb, kb, vb, hidg, ab);

    // feats1 = [partial|hp] @ BtCat^T + boc + feats
    gemm_bt<0, 0, 1><<<dim3(2, 128), 256, 0, stream>>>(ab, BtCat, boc, feats, feats1, MTOT, 256, 512, 256);
    ln_kernel<<<MTOT, 256, 0, stream>>>(feats1, ln_f_g, ln_f_b, hb);
    gemm_bt<1, 1, 0><<<dim3(8, 128), 256, 0, stream>>>(hb, Wf1T, b_ff1, nullptr, ff1b, MTOT, 1024, 256, 1024);
    gemm_bt<0, 0, 1><<<dim3(2, 128), 256, 0, stream>>>(ff1b, Wf2T, b_ff2, feats1, (float*)d_out, MTOT, 256, 1024, 256);
}